// Round 6
// baseline (830.958 us; speedup 1.0000x reference)
//
#include <hip/hip_runtime.h>
#include <hip/hip_bf16.h>
#include <math.h>
#include <string.h>

#define B_    2
#define C_    1536
#define S_    16384
#define H_    768
#define T_    367
#define P_    128
#define HALF_ 384
#define TT_   734                 // 2*T
#define PRED_ELEMS 24051712      // B*P*P*2T

// ws layout (float slots)
#define XH_OFF   0               // [B*4*P][HALF][2] f32 interleaved {x1,x2}  786,432
#define CSF_OFF  786432          // [B*4*P][HALF][2] f32 interleaved {c,s}    786,432
#define INVF_OFF 1572864         // 384 doubles (768 slots)
#define XCB_OFF  1573632         // [B*4*P][C] bf16  (393,216 slots)
// total ~7.9 MB

typedef short short8 __attribute__((ext_vector_type(8)));
typedef float f32x4  __attribute__((ext_vector_type(4)));
typedef float f32x2  __attribute__((ext_vector_type(2)));

__device__ __forceinline__ unsigned int packbf2(float a, float b) {
    __hip_bfloat162 h = __float22bfloat162_rn(make_float2(a, b));
    unsigned int r; __builtin_memcpy(&r, &h, 4); return r;
}
__device__ __forceinline__ unsigned short packbf1(float a) {
    __hip_bfloat16 h = __float2bfloat16(a);
    unsigned short r; __builtin_memcpy(&r, &h, 2); return r;
}

// ---------------- A0: gather embedding columns -> bf16 ----------------
__global__ void gather_cols(const float* __restrict__ emb,
                            const int* __restrict__ sp,
                            unsigned short* __restrict__ xcb) {
    int blk = blockIdx.x;           // B*4*P = 1024
    int p = blk & 127;
    int g = (blk >> 7) & 3;
    int b = blk >> 9;
    int s = sp[(b * 4 + g) * P_ + p];
    const float* src = emb + (size_t)b * C_ * S_ + s;
    unsigned short* dst = xcb + ((size_t)(b * 4 + g) * P_ + p) * C_;
    for (int c = threadIdx.x; c < C_; c += blockDim.x)
        dst[c] = packbf1(src[(size_t)c * S_]);
}

// ---------------- A1: gathered-logits GEMM via bf16 MFMA ----------------
// writes xh interleaved: xh[r][hj*2 + (h>=384)] , hj = h mod 384
__global__ __launch_bounds__(256) void logits_mfma(
    const unsigned short* __restrict__ xcb, const float* __restrict__ w,
    const float* __restrict__ bias, const int* __restrict__ org,
    float* __restrict__ xh) {
    __shared__ __align__(16) unsigned short tX[128 * 64];  // 16KB
    __shared__ __align__(16) unsigned short tW[64 * 64];   // 8KB
    int mt = blockIdx.x;             // 0..7
    int nt = blockIdx.y;             // 0..11
    int o = org[mt >> 2];
    int r0 = mt * 128, h0 = nt * 64;
    int tid = threadIdx.x;
    int lane = tid & 63, wid = tid >> 6;
    int wrow = (wid >> 1) * 64, wcol = (wid & 1) * 32;
    int lr = lane & 15, lq = lane >> 4;
    int gr0 = (lq ^ (lr & 7)) * 8;

    f32x4 acc[4][2];
    #pragma unroll
    for (int i = 0; i < 4; ++i)
        #pragma unroll
        for (int j = 0; j < 2; ++j) acc[i][j] = (f32x4){0.f, 0.f, 0.f, 0.f};

    int xrow = tid >> 1, xhalf = tid & 1;       // X staging: 2 thr/row
    int wr = tid >> 2, wq = tid & 3;            // W staging: 4 thr/row

    for (int kc = 0; kc < C_; kc += 64) {
        if (kc) __syncthreads();
        {   // stage X (bf16 direct)
            const unsigned short* src = xcb + (size_t)(r0 + xrow) * C_ + kc + xhalf * 32;
            unsigned short* drow = tX + xrow * 64;
            #pragma unroll
            for (int i = 0; i < 4; ++i) {
                uint4 v = *(const uint4*)(src + i * 8);
                int g = xhalf * 4 + i;
                *(uint4*)&drow[(g ^ (xrow & 7)) * 8] = v;
            }
        }
        {   // stage W (f32 -> bf16)
            const float* srcw = w + ((size_t)o * H_ + h0 + wr) * C_ + kc + wq * 16;
            unsigned short* drow = tW + wr * 64;
            #pragma unroll
            for (int i = 0; i < 2; ++i) {
                float4 v0 = *(const float4*)(srcw + i * 8);
                float4 v1 = *(const float4*)(srcw + i * 8 + 4);
                uint4 pk;
                pk.x = packbf2(v0.x, v0.y); pk.y = packbf2(v0.z, v0.w);
                pk.z = packbf2(v1.x, v1.y); pk.w = packbf2(v1.z, v1.w);
                int g = wq * 2 + i;
                *(uint4*)&drow[(g ^ (wr & 7)) * 8] = pk;
            }
        }
        __syncthreads();
        #pragma unroll
        for (int kk = 0; kk < 64; kk += 32) {
            short8 af[4], bf2[2];
            #pragma unroll
            for (int fi = 0; fi < 4; ++fi)
                af[fi] = *(const short8*)&tX[(wrow + fi * 16 + lr) * 64 + (gr0 ^ kk)];
            #pragma unroll
            for (int fj = 0; fj < 2; ++fj)
                bf2[fj] = *(const short8*)&tW[(wcol + fj * 16 + lr) * 64 + (gr0 ^ kk)];
            #pragma unroll
            for (int fi = 0; fi < 4; ++fi)
                #pragma unroll
                for (int fj = 0; fj < 2; ++fj)
                    acc[fi][fj] = __builtin_amdgcn_mfma_f32_16x16x32_bf16(
                        af[fi], bf2[fj], acc[fi][fj], 0, 0, 0);
        }
    }
    #pragma unroll
    for (int fi = 0; fi < 4; ++fi)
        #pragma unroll
        for (int rr = 0; rr < 4; ++rr) {
            int r = r0 + wrow + fi * 16 + lq * 4 + rr;
            #pragma unroll
            for (int fj = 0; fj < 2; ++fj) {
                int h = h0 + wcol + fj * 16 + lr;
                int hj = (h < HALF_) ? h : (h - HALF_);
                int sel = (h < HALF_) ? 0 : 1;
                xh[(size_t)r * H_ + hj * 2 + sel] = acc[fi][fj][rr] + bias[o * H_ + h];
            }
        }
}

// ---------------- A2a: inv-freq table (fp64) ----------------
__global__ void init_invf(double* __restrict__ invf) {
    int j = threadIdx.x;
    if (j < HALF_) invf[j] = exp2(-20.0 * (double)j / 384.0);
}

// ---------------- A2b: RoPE cos/sin table, interleaved {c,s} f32 ----------------
__global__ void rope_table(const int* __restrict__ sp,
                           const double* __restrict__ invf,
                           float2* __restrict__ csf) {
    int e = blockIdx.x * blockDim.x + threadIdx.x;  // 1024*384
    if (e >= B_ * 4 * P_ * HALF_) return;
    int j = e % HALF_;
    int r = e / HALF_;
    int s = sp[r];
    const double TWO_PI = 6.283185307179586476925286766559;
    double ang = (double)s * invf[j];
    double k = rint(ang * (1.0 / TWO_PI));
    float fr = (float)(ang - k * TWO_PI);
    float sv, cv;
    __sincosf(fr, &sv, &cv);
    csf[e] = make_float2(cv, sv);
}

// ---------------- B: junction GEMM via bf16 MFMA ----------------
// block = one (b,sign,t), 512 thr = 8 waves, each 64x32 of 128x128 out.
// K=768 as 24 chunks of 32 k (16 pairs). Double-buffered 32KB LDS,
// 1 barrier/chunk, 4 blocks/CU target.
__global__ __launch_bounds__(512, 8) void junction_mfma(
    const float* __restrict__ xh, const float* __restrict__ csf,
    const float* __restrict__ rpd, const float* __restrict__ rpa,
    const float* __restrict__ rnd, const float* __restrict__ rna,
    const int* __restrict__ org, const int* __restrict__ sp,
    unsigned short* __restrict__ w1) {
    __shared__ __align__(16) unsigned short smem[16384];  // 32KB: [2 buf][tD|tA][128*32]
    __shared__ int vD[P_], vA[P_];

    // bijective XCD swizzle (nwg = 1468, nwg%8 = 4)
    int nwg = gridDim.x;
    int orig = blockIdx.x;
    int xcd = orig & 7;
    int q = nwg >> 3, r8 = nwg & 7;
    int blk = (xcd < r8 ? xcd * (q + 1) : r8 * (q + 1) + (xcd - r8) * q) + (orig >> 3);

    int t = blk % T_;
    int sign = (blk / T_) & 1;
    int b = blk / (2 * T_);
    int o = org[b];
    int gd = sign * 2, ga = sign * 2 + 1;
    const float* pd = sign ? rnd : rpd;
    const float* pa = sign ? rna : rpa;
    int tid = threadIdx.x;

    const float* sc_d = pd + ((size_t)(o * 2 + 0) * T_ + t) * H_;
    const float* of_d = pd + ((size_t)(o * 2 + 1) * T_ + t) * H_;
    const float* sc_a = pa + ((size_t)(o * 2 + 0) * T_ + t) * H_;
    const float* of_a = pa + ((size_t)(o * 2 + 1) * T_ + t) * H_;

    if (tid < P_) {
        vD[tid] = sp[(b * 4 + gd) * P_ + tid] >= 0;
        vA[tid] = sp[(b * 4 + ga) * P_ + tid] >= 0;
    }
    const float* xd = xh + ((size_t)(b * 4 + gd) * P_) * H_;   // row stride 768 (interleaved)
    const float* xa = xh + ((size_t)(b * 4 + ga) * P_) * H_;
    const float* cd = csf + ((size_t)(b * 4 + gd) * P_) * H_;  // float2[384] per row = 768 f32
    const float* ca = csf + ((size_t)(b * 4 + ga) * P_) * H_;

    int lane = tid & 63, wid = tid >> 6;
    int wrow = (wid >> 2) * 64, wcol = (wid & 3) * 32;
    int lr = lane & 15, lq = lane >> 4;
    int gr0 = (lq ^ (lr & 3)) * 8;     // read granule (8 ushorts) within 32-ushort row

    f32x4 acc[4][2];
    #pragma unroll
    for (int i = 0; i < 4; ++i)
        #pragma unroll
        for (int j = 0; j < 2; ++j) acc[i][j] = (f32x4){0.f, 0.f, 0.f, 0.f};

    int jp = tid & 7;         // pk-group: pairs {2jp, 2jp+1} within 16-pair chunk
    int prow = tid >> 3;      // 0..63; p = pass*64 + prow, 2 passes
    int swbase = (((jp >> 1)) << 3) + ((jp & 1) << 2);   // pre-XOR ushort offset

    for (int ch = 0; ch < 24; ++ch) {
        int jb = ch * 16 + 2 * jp;
        unsigned short* tDc = smem + (ch & 1) * 8192;
        unsigned short* tAc = tDc + 4096;

        // per-chunk coefs (8B loads, shared across prow -> L1 broadcast)
        f32x2 s1d = *(const f32x2*)(sc_d + jb);
        f32x2 o1d = *(const f32x2*)(of_d + jb);
        f32x2 s2d = *(const f32x2*)(sc_d + jb + HALF_);
        f32x2 o2d = *(const f32x2*)(of_d + jb + HALF_);
        f32x2 s1a = *(const f32x2*)(sc_a + jb);
        f32x2 o1a = *(const f32x2*)(of_a + jb);
        f32x2 s2a = *(const f32x2*)(sc_a + jb + HALF_);
        f32x2 o2a = *(const f32x2*)(of_a + jb + HALF_);

        if (ch) __syncthreads();   // all waves done MFMA(ch-1) -> safe to overwrite buf (ch-2)

        #pragma unroll
        for (int pass = 0; pass < 2; ++pass) {
            int p = pass * 64 + prow;
            int sw = p * 32 + (swbase ^ ((p & 3) << 3));
            {   // donor
                float4 xv = *(const float4*)(xd + p * H_ + 2 * jb); // x1[j],x2[j],x1[j+1],x2[j+1]
                float4 cv = *(const float4*)(cd + p * H_ + 2 * jb); // c[j],s[j],c[j+1],s[j+1]
                float u1 = fmaf(s1d.x, xv.x, o1d.x);
                float u2 = fmaf(s2d.x, xv.y, o2d.x);
                float r1 = u1 * cv.x - u2 * cv.y;
                float r2 = u1 * cv.y + u2 * cv.x;
                float u3 = fmaf(s1d.y, xv.z, o1d.y);
                float u4 = fmaf(s2d.y, xv.w, o2d.y);
                float r3 = u3 * cv.z - u4 * cv.w;
                float r4 = u3 * cv.w + u4 * cv.z;
                uint2 wv;
                wv.x = packbf2(r1, r2);
                wv.y = packbf2(r3, r4);
                *(uint2*)&tDc[sw] = wv;
            }
            {   // acceptor
                float4 xv = *(const float4*)(xa + p * H_ + 2 * jb);
                float4 cv = *(const float4*)(ca + p * H_ + 2 * jb);
                float u1 = fmaf(s1a.x, xv.x, o1a.x);
                float u2 = fmaf(s2a.x, xv.y, o2a.x);
                float r1 = u1 * cv.x - u2 * cv.y;
                float r2 = u1 * cv.y + u2 * cv.x;
                float u3 = fmaf(s1a.y, xv.z, o1a.y);
                float u4 = fmaf(s2a.y, xv.w, o2a.y);
                float r3 = u3 * cv.z - u4 * cv.w;
                float r4 = u3 * cv.w + u4 * cv.z;
                uint2 wv;
                wv.x = packbf2(r1, r2);
                wv.y = packbf2(r3, r4);
                *(uint2*)&tAc[sw] = wv;
            }
        }
        __syncthreads();

        __builtin_amdgcn_s_setprio(1);
        {
            short8 af[4], bf2[2];
            #pragma unroll
            for (int fi = 0; fi < 4; ++fi)
                af[fi] = *(const short8*)&tDc[(wrow + fi * 16 + lr) * 32 + gr0];
            #pragma unroll
            for (int fj = 0; fj < 2; ++fj)
                bf2[fj] = *(const short8*)&tAc[(wcol + fj * 16 + lr) * 32 + gr0];
            #pragma unroll
            for (int fi = 0; fi < 4; ++fi)
                #pragma unroll
                for (int fj = 0; fj < 2; ++fj)
                    acc[fi][fj] = __builtin_amdgcn_mfma_f32_16x16x32_bf16(
                        af[fi], bf2[fj], acc[fi][fj], 0, 0, 0);
        }
        __builtin_amdgcn_s_setprio(0);
    }

    // ---- epilogue: softplus+mask -> bf16 LDS stage (full 32KB) -> coalesced copy ----
    __syncthreads();               // all MFMA reads of smem done before restage
    #pragma unroll
    for (int fi = 0; fi < 4; ++fi) {
        #pragma unroll
        for (int rr = 0; rr < 4; ++rr) {
            int d = wrow + fi * 16 + lq * 4 + rr;
            int vd = vD[d];
            #pragma unroll
            for (int fj = 0; fj < 2; ++fj) {
                int a = wcol + fj * 16 + lr;
                float x = acc[fi][fj][rr];
                float v = 0.0f;
                if (vd && vA[a]) v = (x > 15.0f) ? x : log1pf(__expf(x));
                smem[d * P_ + a] = packbf1(v);
            }
        }
    }
    __syncthreads();
    const uint4* src4 = (const uint4*)smem;                       // 2048 uint4
    uint4* dst4 = (uint4*)(w1 + ((size_t)((b * 2 + sign) * T_ + t) * P_) * P_);
    for (int i = tid; i < 2048; i += 512) dst4[i] = src4[i];
}

// ---------------- C: transpose bf16 [b][sign][t][d][a] -> f32 [b][d][a][sign*T+t] ----------------
__global__ __launch_bounds__(256) void transpose_out(const __hip_bfloat16* __restrict__ w1,
                                                     float* __restrict__ pred) {
    __shared__ float tile[64 * 129];
    int blk = blockIdx.x;            // bs*128*6 + d*6 + tt   (3072 blocks)
    int tt = blk % 6;
    int d = (blk / 6) % P_;
    int bs = blk / (6 * P_);         // b*2+sign
    int b = bs >> 1, sign = bs & 1;
    int t0 = tt * 64;
    int tcnt = min(64, T_ - t0);
    int tid = threadIdx.x;

    const __hip_bfloat16* src = w1 + (size_t)bs * T_ * P_ * P_ + (size_t)d * P_;
    for (int e = tid; e < tcnt * P_; e += 256) {
        int i = e >> 7, a = e & 127;
        tile[i * 129 + a] = __bfloat162float(src[(size_t)(t0 + i) * P_ * P_ + a]);
    }
    __syncthreads();
    float* dst = pred + ((size_t)(b * P_ + d) * P_) * TT_ + sign * T_ + t0;
    for (int e = tid; e < P_ * 64; e += 256) {
        int a = e >> 6, ii = e & 63;
        if (ii < tcnt) dst[(size_t)a * TT_ + ii] = tile[ii * 129 + a];
    }
}

// ---------------- D: mask fill ----------------
__global__ void mask_fill(const int* __restrict__ sp, float* __restrict__ mask) {
    int blk = blockIdx.x;            // (b*128+d)*128+a   (32768 blocks)
    int a = blk & 127;
    int d = (blk >> 7) & 127;
    int b = blk >> 14;
    bool vp = (sp[(b * 4 + 0) * P_ + d] >= 0) && (sp[(b * 4 + 1) * P_ + a] >= 0);
    bool vn = (sp[(b * 4 + 2) * P_ + d] >= 0) && (sp[(b * 4 + 3) * P_ + a] >= 0);
    float* dst = mask + (size_t)blk * TT_;
    for (int st = threadIdx.x; st < TT_; st += blockDim.x)
        dst[st] = (st < T_ ? vp : vn) ? 1.0f : 0.0f;
}

extern "C" void kernel_launch(void* const* d_in, const int* in_sizes, int n_in,
                              void* d_out, int out_size, void* d_ws, size_t ws_size,
                              hipStream_t stream) {
    const float* emb  = (const float*)d_in[0];
    const float* w    = (const float*)d_in[1];
    const float* bias = (const float*)d_in[2];
    const float* rpd  = (const float*)d_in[3];
    const float* rpa  = (const float*)d_in[4];
    const float* rnd  = (const float*)d_in[5];
    const float* rna  = (const float*)d_in[6];
    const int*   org  = (const int*)d_in[7];
    const int*   sp   = (const int*)d_in[8];

    float* out = (float*)d_out;
    float* ws  = (float*)d_ws;
    float* xh   = ws + XH_OFF;
    float* csf  = ws + CSF_OFF;
    double* invf = (double*)(ws + INVF_OFF);
    unsigned short* xcb = (unsigned short*)(ws + XCB_OFF);
    float* pred  = out;
    float* maskp = out + PRED_ELEMS;
    unsigned short* w1 = (unsigned short*)maskp;   // bf16 staging in mask half

    init_invf<<<1, 384, 0, stream>>>(invf);
    gather_cols<<<1024, 256, 0, stream>>>(emb, sp, xcb);
    rope_table<<<1536, 256, 0, stream>>>(sp, invf, (float2*)csf);
    dim3 gl(8, 12);
    logits_mfma<<<gl, 256, 0, stream>>>(xcb, w, bias, org, xh);
    junction_mfma<<<2 * 2 * T_, 512, 0, stream>>>(xh, csf, rpd, rpa, rnd, rna, org, sp, w1);
    transpose_out<<<2 * 2 * P_ * 6, 256, 0, stream>>>((const __hip_bfloat16*)w1, pred);
    mask_fill<<<32768, 256, 0, stream>>>(sp, maskp);
}

// Round 7
// 455.468 us; speedup vs baseline: 1.8244x; 1.8244x over previous
//
#include <hip/hip_runtime.h>
#include <hip/hip_bf16.h>
#include <math.h>
#include <string.h>

#define B_    2
#define C_    1536
#define S_    16384
#define H_    768
#define T_    367
#define P_    128
#define HALF_ 384
#define TT_   734                 // 2*T
#define PRED_ELEMS 24051712      // B*P*P*2T

// ws layout (float slots)
#define XH_OFF   0               // [B*4*P][HALF][2] f32 interleaved {x1,x2}  786,432
#define CSF_OFF  786432          // [B*4*P][HALF][2] f32 interleaved {c,s}    786,432
#define INVF_OFF 1572864         // 384 doubles (768 slots)
#define XCB_OFF  1573632         // [B*4*P][C] bf16  (393,216 slots)

typedef short short8 __attribute__((ext_vector_type(8)));
typedef float f32x4  __attribute__((ext_vector_type(4)));
typedef float f32x2  __attribute__((ext_vector_type(2)));

__device__ __forceinline__ unsigned int packbf2(float a, float b) {
    __hip_bfloat162 h = __float22bfloat162_rn(make_float2(a, b));
    unsigned int r; __builtin_memcpy(&r, &h, 4); return r;
}
__device__ __forceinline__ unsigned short packbf1(float a) {
    __hip_bfloat16 h = __float2bfloat16(a);
    unsigned short r; __builtin_memcpy(&r, &h, 2); return r;
}

// ---------------- A0: gather embedding columns -> bf16 ----------------
__global__ void gather_cols(const float* __restrict__ emb,
                            const int* __restrict__ sp,
                            unsigned short* __restrict__ xcb) {
    int blk = blockIdx.x;           // B*4*P = 1024
    int p = blk & 127;
    int g = (blk >> 7) & 3;
    int b = blk >> 9;
    int s = sp[(b * 4 + g) * P_ + p];
    const float* src = emb + (size_t)b * C_ * S_ + s;
    unsigned short* dst = xcb + ((size_t)(b * 4 + g) * P_ + p) * C_;
    for (int c = threadIdx.x; c < C_; c += blockDim.x)
        dst[c] = packbf1(src[(size_t)c * S_]);
}

// ---------------- A1: gathered-logits GEMM via bf16 MFMA ----------------
// writes xh interleaved: xh[r][hj*2 + (h>=384)] , hj = h mod 384
__global__ __launch_bounds__(256) void logits_mfma(
    const unsigned short* __restrict__ xcb, const float* __restrict__ w,
    const float* __restrict__ bias, const int* __restrict__ org,
    float* __restrict__ xh) {
    __shared__ __align__(16) unsigned short tX[128 * 64];  // 16KB
    __shared__ __align__(16) unsigned short tW[64 * 64];   // 8KB
    int mt = blockIdx.x;             // 0..7
    int nt = blockIdx.y;             // 0..11
    int o = org[mt >> 2];
    int r0 = mt * 128, h0 = nt * 64;
    int tid = threadIdx.x;
    int lane = tid & 63, wid = tid >> 6;
    int wrow = (wid >> 1) * 64, wcol = (wid & 1) * 32;
    int lr = lane & 15, lq = lane >> 4;
    int gr0 = (lq ^ (lr & 7)) * 8;

    f32x4 acc[4][2];
    #pragma unroll
    for (int i = 0; i < 4; ++i)
        #pragma unroll
        for (int j = 0; j < 2; ++j) acc[i][j] = (f32x4){0.f, 0.f, 0.f, 0.f};

    int xrow = tid >> 1, xhalf = tid & 1;       // X staging: 2 thr/row
    int wr = tid >> 2, wq = tid & 3;            // W staging: 4 thr/row

    for (int kc = 0; kc < C_; kc += 64) {
        if (kc) __syncthreads();
        {   // stage X (bf16 direct)
            const unsigned short* src = xcb + (size_t)(r0 + xrow) * C_ + kc + xhalf * 32;
            unsigned short* drow = tX + xrow * 64;
            #pragma unroll
            for (int i = 0; i < 4; ++i) {
                uint4 v = *(const uint4*)(src + i * 8);
                int g = xhalf * 4 + i;
                *(uint4*)&drow[(g ^ (xrow & 7)) * 8] = v;
            }
        }
        {   // stage W (f32 -> bf16)
            const float* srcw = w + ((size_t)o * H_ + h0 + wr) * C_ + kc + wq * 16;
            unsigned short* drow = tW + wr * 64;
            #pragma unroll
            for (int i = 0; i < 2; ++i) {
                float4 v0 = *(const float4*)(srcw + i * 8);
                float4 v1 = *(const float4*)(srcw + i * 8 + 4);
                uint4 pk;
                pk.x = packbf2(v0.x, v0.y); pk.y = packbf2(v0.z, v0.w);
                pk.z = packbf2(v1.x, v1.y); pk.w = packbf2(v1.z, v1.w);
                int g = wq * 2 + i;
                *(uint4*)&drow[(g ^ (wr & 7)) * 8] = pk;
            }
        }
        __syncthreads();
        #pragma unroll
        for (int kk = 0; kk < 64; kk += 32) {
            short8 af[4], bf2[2];
            #pragma unroll
            for (int fi = 0; fi < 4; ++fi)
                af[fi] = *(const short8*)&tX[(wrow + fi * 16 + lr) * 64 + (gr0 ^ kk)];
            #pragma unroll
            for (int fj = 0; fj < 2; ++fj)
                bf2[fj] = *(const short8*)&tW[(wcol + fj * 16 + lr) * 64 + (gr0 ^ kk)];
            #pragma unroll
            for (int fi = 0; fi < 4; ++fi)
                #pragma unroll
                for (int fj = 0; fj < 2; ++fj)
                    acc[fi][fj] = __builtin_amdgcn_mfma_f32_16x16x32_bf16(
                        af[fi], bf2[fj], acc[fi][fj], 0, 0, 0);
        }
    }
    #pragma unroll
    for (int fi = 0; fi < 4; ++fi)
        #pragma unroll
        for (int rr = 0; rr < 4; ++rr) {
            int r = r0 + wrow + fi * 16 + lq * 4 + rr;
            #pragma unroll
            for (int fj = 0; fj < 2; ++fj) {
                int h = h0 + wcol + fj * 16 + lr;
                int hj = (h < HALF_) ? h : (h - HALF_);
                int sel = (h < HALF_) ? 0 : 1;
                xh[(size_t)r * H_ + hj * 2 + sel] = acc[fi][fj][rr] + bias[o * H_ + h];
            }
        }
}

// ---------------- A2a: inv-freq table (fp64) ----------------
__global__ void init_invf(double* __restrict__ invf) {
    int j = threadIdx.x;
    if (j < HALF_) invf[j] = exp2(-20.0 * (double)j / 384.0);
}

// ---------------- A2b: RoPE cos/sin table, interleaved {c,s} f32 ----------------
__global__ void rope_table(const int* __restrict__ sp,
                           const double* __restrict__ invf,
                           float2* __restrict__ csf) {
    int e = blockIdx.x * blockDim.x + threadIdx.x;  // 1024*384
    if (e >= B_ * 4 * P_ * HALF_) return;
    int j = e % HALF_;
    int r = e / HALF_;
    int s = sp[r];
    const double TWO_PI = 6.283185307179586476925286766559;
    double ang = (double)s * invf[j];
    double k = rint(ang * (1.0 / TWO_PI));
    float fr = (float)(ang - k * TWO_PI);
    float sv, cv;
    __sincosf(fr, &sv, &cv);
    csf[e] = make_float2(cv, sv);
}

// ---------------- B: junction GEMM via bf16 MFMA ----------------
// block = one (b,sign,t), 512 thr = 8 waves, each 64x32 of 128x128 out.
// K=768 as 12 chunks of 64 k (32 pairs). SINGLE 32KB LDS buffer (128B rows,
// proven 2-way-free swizzle), 2 barriers/chunk, 3 blocks/CU (VGPR cap 84).
__global__ __launch_bounds__(512, 6) void junction_mfma(
    const float* __restrict__ xh, const float* __restrict__ csf,
    const float* __restrict__ rpd, const float* __restrict__ rpa,
    const float* __restrict__ rnd, const float* __restrict__ rna,
    const int* __restrict__ org, const int* __restrict__ sp,
    unsigned short* __restrict__ w1) {
    __shared__ __align__(16) unsigned short smem[16384];  // 32KB: tD | tA, 128x64 each
    __shared__ int vD[P_], vA[P_];
    unsigned short* tD = smem;          // rows of 64 ushorts = 128B
    unsigned short* tA = smem + 8192;

    // bijective XCD swizzle (nwg = 1468, nwg%8 = 4)
    int nwg = gridDim.x;
    int orig = blockIdx.x;
    int xcd = orig & 7;
    int q = nwg >> 3, r8 = nwg & 7;
    int blk = (xcd < r8 ? xcd * (q + 1) : r8 * (q + 1) + (xcd - r8) * q) + (orig >> 3);

    int t = blk % T_;
    int sign = (blk / T_) & 1;
    int b = blk / (2 * T_);
    int o = org[b];
    int gd = sign * 2, ga = sign * 2 + 1;
    const float* pd = sign ? rnd : rpd;
    const float* pa = sign ? rna : rpa;
    int tid = threadIdx.x;

    const float* sc_d = pd + ((size_t)(o * 2 + 0) * T_ + t) * H_;
    const float* of_d = pd + ((size_t)(o * 2 + 1) * T_ + t) * H_;
    const float* sc_a = pa + ((size_t)(o * 2 + 0) * T_ + t) * H_;
    const float* of_a = pa + ((size_t)(o * 2 + 1) * T_ + t) * H_;

    if (tid < P_) {
        vD[tid] = sp[(b * 4 + gd) * P_ + tid] >= 0;
        vA[tid] = sp[(b * 4 + ga) * P_ + tid] >= 0;
    }
    const float* xd = xh + ((size_t)(b * 4 + gd) * P_) * H_;   // interleaved {x1,x2}
    const float* xa = xh + ((size_t)(b * 4 + ga) * P_) * H_;
    const float* cd = csf + ((size_t)(b * 4 + gd) * P_) * H_;  // interleaved {c,s}
    const float* ca = csf + ((size_t)(b * 4 + ga) * P_) * H_;

    int lane = tid & 63, wid = tid >> 6;
    int wrow = (wid >> 2) * 64, wcol = (wid & 3) * 32;
    int lr = lane & 15, lq = lane >> 4;
    int gr0 = (lq ^ (lr & 7)) * 8;     // read granule within 64-ushort row

    f32x4 acc[4][2];
    #pragma unroll
    for (int i = 0; i < 4; ++i)
        #pragma unroll
        for (int j = 0; j < 2; ++j) acc[i][j] = (f32x4){0.f, 0.f, 0.f, 0.f};

    int jp = tid & 15;        // pairs {2jp, 2jp+1} of the 32-pair chunk
    int prow = tid >> 4;      // 0..31; p = pass*32 + prow, 4 passes

    for (int ch = 0; ch < 12; ++ch) {
        int jb = ch * 32 + 2 * jp;
        // per-chunk coefs (8B loads, broadcast-shared across prow)
        f32x2 s1d = *(const f32x2*)(sc_d + jb);
        f32x2 o1d = *(const f32x2*)(of_d + jb);
        f32x2 s2d = *(const f32x2*)(sc_d + jb + HALF_);
        f32x2 o2d = *(const f32x2*)(of_d + jb + HALF_);
        f32x2 s1a = *(const f32x2*)(sc_a + jb);
        f32x2 o1a = *(const f32x2*)(of_a + jb);
        f32x2 s2a = *(const f32x2*)(sc_a + jb + HALF_);
        f32x2 o2a = *(const f32x2*)(of_a + jb + HALF_);

        if (ch) __syncthreads();   // all MFMA(ch-1) reads done -> safe to overwrite

        #pragma unroll
        for (int pass = 0; pass < 4; ++pass) {
            int p = pass * 32 + prow;
            int sw = p * 64 + (((jp >> 1) ^ (p & 7)) << 3) + ((jp & 1) << 2);
            {   // donor
                float4 xv = *(const float4*)(xd + p * H_ + 2 * jb); // x1[j],x2[j],x1[j+1],x2[j+1]
                float4 cv = *(const float4*)(cd + p * H_ + 2 * jb); // c[j],s[j],c[j+1],s[j+1]
                float u1 = fmaf(s1d.x, xv.x, o1d.x);
                float u2 = fmaf(s2d.x, xv.y, o2d.x);
                float r1 = u1 * cv.x - u2 * cv.y;
                float r2 = u1 * cv.y + u2 * cv.x;
                float u3 = fmaf(s1d.y, xv.z, o1d.y);
                float u4 = fmaf(s2d.y, xv.w, o2d.y);
                float r3 = u3 * cv.z - u4 * cv.w;
                float r4 = u3 * cv.w + u4 * cv.z;
                uint2 wv;
                wv.x = packbf2(r1, r2);
                wv.y = packbf2(r3, r4);
                *(uint2*)&tD[sw] = wv;
            }
            {   // acceptor
                float4 xv = *(const float4*)(xa + p * H_ + 2 * jb);
                float4 cv = *(const float4*)(ca + p * H_ + 2 * jb);
                float u1 = fmaf(s1a.x, xv.x, o1a.x);
                float u2 = fmaf(s2a.x, xv.y, o2a.x);
                float r1 = u1 * cv.x - u2 * cv.y;
                float r2 = u1 * cv.y + u2 * cv.x;
                float u3 = fmaf(s1a.y, xv.z, o1a.y);
                float u4 = fmaf(s2a.y, xv.w, o2a.y);
                float r3 = u3 * cv.z - u4 * cv.w;
                float r4 = u3 * cv.w + u4 * cv.z;
                uint2 wv;
                wv.x = packbf2(r1, r2);
                wv.y = packbf2(r3, r4);
                *(uint2*)&tA[sw] = wv;
            }
        }
        __syncthreads();

        __builtin_amdgcn_s_setprio(1);
        #pragma unroll
        for (int kk = 0; kk < 64; kk += 32) {
            short8 af[4], bf2[2];
            #pragma unroll
            for (int fi = 0; fi < 4; ++fi)
                af[fi] = *(const short8*)&tD[(wrow + fi * 16 + lr) * 64 + (gr0 ^ kk)];
            #pragma unroll
            for (int fj = 0; fj < 2; ++fj)
                bf2[fj] = *(const short8*)&tA[(wcol + fj * 16 + lr) * 64 + (gr0 ^ kk)];
            #pragma unroll
            for (int fi = 0; fi < 4; ++fi)
                #pragma unroll
                for (int fj = 0; fj < 2; ++fj)
                    acc[fi][fj] = __builtin_amdgcn_mfma_f32_16x16x32_bf16(
                        af[fi], bf2[fj], acc[fi][fj], 0, 0, 0);
        }
        __builtin_amdgcn_s_setprio(0);
    }

    // ---- epilogue: softplus+mask -> bf16 LDS stage (32KB) -> coalesced copy ----
    __syncthreads();               // all MFMA reads of smem done before restage
    #pragma unroll
    for (int fi = 0; fi < 4; ++fi) {
        #pragma unroll
        for (int rr = 0; rr < 4; ++rr) {
            int d = wrow + fi * 16 + lq * 4 + rr;
            int vd = vD[d];
            #pragma unroll
            for (int fj = 0; fj < 2; ++fj) {
                int a = wcol + fj * 16 + lr;
                float x = acc[fi][fj][rr];
                float v = 0.0f;
                if (vd && vA[a]) v = (x > 15.0f) ? x : log1pf(__expf(x));
                smem[d * P_ + a] = packbf1(v);
            }
        }
    }
    __syncthreads();
    const uint4* src4 = (const uint4*)smem;                       // 2048 uint4
    uint4* dst4 = (uint4*)(w1 + ((size_t)((b * 2 + sign) * T_ + t) * P_) * P_);
    for (int i = tid; i < 2048; i += 512) dst4[i] = src4[i];
}

// ---------------- C: transpose bf16 [b][sign][t][d][a] -> f32 [b][d][a][sign*T+t] ----------------
__global__ __launch_bounds__(256) void transpose_out(const __hip_bfloat16* __restrict__ w1,
                                                     float* __restrict__ pred) {
    __shared__ float tile[64 * 129];
    int blk = blockIdx.x;            // bs*128*6 + d*6 + tt   (3072 blocks)
    int tt = blk % 6;
    int d = (blk / 6) % P_;
    int bs = blk / (6 * P_);         // b*2+sign
    int b = bs >> 1, sign = bs & 1;
    int t0 = tt * 64;
    int tcnt = min(64, T_ - t0);
    int tid = threadIdx.x;

    const __hip_bfloat16* src = w1 + (size_t)bs * T_ * P_ * P_ + (size_t)d * P_;
    for (int e = tid; e < tcnt * P_; e += 256) {
        int i = e >> 7, a = e & 127;
        tile[i * 129 + a] = __bfloat162float(src[(size_t)(t0 + i) * P_ * P_ + a]);
    }
    __syncthreads();
    float* dst = pred + ((size_t)(b * P_ + d) * P_) * TT_ + sign * T_ + t0;
    for (int e = tid; e < P_ * 64; e += 256) {
        int a = e >> 6, ii = e & 63;
        if (ii < tcnt) dst[(size_t)a * TT_ + ii] = tile[ii * 129 + a];
    }
}

// ---------------- D: mask fill ----------------
__global__ void mask_fill(const int* __restrict__ sp, float* __restrict__ mask) {
    int blk = blockIdx.x;            // (b*128+d)*128+a   (32768 blocks)
    int a = blk & 127;
    int d = (blk >> 7) & 127;
    int b = blk >> 14;
    bool vp = (sp[(b * 4 + 0) * P_ + d] >= 0) && (sp[(b * 4 + 1) * P_ + a] >= 0);
    bool vn = (sp[(b * 4 + 2) * P_ + d] >= 0) && (sp[(b * 4 + 3) * P_ + a] >= 0);
    float* dst = mask + (size_t)blk * TT_;
    for (int st = threadIdx.x; st < TT_; st += blockDim.x)
        dst[st] = (st < T_ ? vp : vn) ? 1.0f : 0.0f;
}

extern "C" void kernel_launch(void* const* d_in, const int* in_sizes, int n_in,
                              void* d_out, int out_size, void* d_ws, size_t ws_size,
                              hipStream_t stream) {
    const float* emb  = (const float*)d_in[0];
    const float* w    = (const float*)d_in[1];
    const float* bias = (const float*)d_in[2];
    const float* rpd  = (const float*)d_in[3];
    const float* rpa  = (const float*)d_in[4];
    const float* rnd  = (const float*)d_in[5];
    const float* rna  = (const float*)d_in[6];
    const int*   org  = (const int*)d_in[7];
    const int*   sp   = (const int*)d_in[8];

    float* out = (float*)d_out;
    float* ws  = (float*)d_ws;
    float* xh   = ws + XH_OFF;
    float* csf  = ws + CSF_OFF;
    double* invf = (double*)(ws + INVF_OFF);
    unsigned short* xcb = (unsigned short*)(ws + XCB_OFF);
    float* pred  = out;
    float* maskp = out + PRED_ELEMS;
    unsigned short* w1 = (unsigned short*)maskp;   // bf16 staging in mask half

    init_invf<<<1, 384, 0, stream>>>(invf);
    gather_cols<<<1024, 256, 0, stream>>>(emb, sp, xcb);
    rope_table<<<1536, 256, 0, stream>>>(sp, invf, (float2*)csf);
    dim3 gl(8, 12);
    logits_mfma<<<gl, 256, 0, stream>>>(xcb, w, bias, org, xh);
    junction_mfma<<<2 * 2 * T_, 512, 0, stream>>>(xh, csf, rpd, rpa, rnd, rna, org, sp, w1);
    transpose_out<<<2 * 2 * P_ * 6, 256, 0, stream>>>((const __hip_bfloat16*)w1, pred);
    mask_fill<<<32768, 256, 0, stream>>>(sp, maskp);
}

// Round 8
// 350.753 us; speedup vs baseline: 2.3691x; 1.2985x over previous
//
#include <hip/hip_runtime.h>
#include <hip/hip_bf16.h>
#include <math.h>
#include <string.h>

#define B_    2
#define C_    1536
#define S_    16384
#define H_    768
#define T_    367
#define P_    128
#define HALF_ 384
#define TT_   734                 // 2*T
#define PRED_ELEMS 24051712      // B*P*P*2T

// ws layout (float slots)
#define XH_OFF   0               // [B*4*P][HALF][2] f32 interleaved {x1,x2}  786,432
#define CSF_OFF  786432          // [B*4*P][HALF][2] f32 interleaved {c,s}    786,432
#define INVF_OFF 1572864         // 384 doubles (768 slots)
#define XCB_OFF  1573632         // [B*4*P][C] bf16  (393,216 slots)

typedef short short8 __attribute__((ext_vector_type(8)));
typedef float f32x4  __attribute__((ext_vector_type(4)));
typedef float f32x2  __attribute__((ext_vector_type(2)));

__device__ __forceinline__ unsigned int packbf2(float a, float b) {
    __hip_bfloat162 h = __float22bfloat162_rn(make_float2(a, b));
    unsigned int r; __builtin_memcpy(&r, &h, 4); return r;
}
__device__ __forceinline__ unsigned short packbf1(float a) {
    __hip_bfloat16 h = __float2bfloat16(a);
    unsigned short r; __builtin_memcpy(&r, &h, 2); return r;
}

// ---------------- A0: gather embedding columns -> bf16 ----------------
__global__ void gather_cols(const float* __restrict__ emb,
                            const int* __restrict__ sp,
                            unsigned short* __restrict__ xcb) {
    int blk = blockIdx.x;           // B*4*P = 1024
    int p = blk & 127;
    int g = (blk >> 7) & 3;
    int b = blk >> 9;
    int s = sp[(b * 4 + g) * P_ + p];
    const float* src = emb + (size_t)b * C_ * S_ + s;
    unsigned short* dst = xcb + ((size_t)(b * 4 + g) * P_ + p) * C_;
    for (int c = threadIdx.x; c < C_; c += blockDim.x)
        dst[c] = packbf1(src[(size_t)c * S_]);
}

// ---------------- A1: gathered-logits GEMM via bf16 MFMA ----------------
// writes xh interleaved: xh[r][hj*2 + (h>=384)] , hj = h mod 384
__global__ __launch_bounds__(256) void logits_mfma(
    const unsigned short* __restrict__ xcb, const float* __restrict__ w,
    const float* __restrict__ bias, const int* __restrict__ org,
    float* __restrict__ xh) {
    __shared__ __align__(16) unsigned short tX[128 * 64];  // 16KB
    __shared__ __align__(16) unsigned short tW[64 * 64];   // 8KB
    int mt = blockIdx.x;             // 0..7
    int nt = blockIdx.y;             // 0..11
    int o = org[mt >> 2];
    int r0 = mt * 128, h0 = nt * 64;
    int tid = threadIdx.x;
    int lane = tid & 63, wid = tid >> 6;
    int wrow = (wid >> 1) * 64, wcol = (wid & 1) * 32;
    int lr = lane & 15, lq = lane >> 4;
    int gr0 = (lq ^ (lr & 7)) * 8;

    f32x4 acc[4][2];
    #pragma unroll
    for (int i = 0; i < 4; ++i)
        #pragma unroll
        for (int j = 0; j < 2; ++j) acc[i][j] = (f32x4){0.f, 0.f, 0.f, 0.f};

    int xrow = tid >> 1, xhalf = tid & 1;       // X staging: 2 thr/row
    int wr = tid >> 2, wq = tid & 3;            // W staging: 4 thr/row

    for (int kc = 0; kc < C_; kc += 64) {
        if (kc) __syncthreads();
        {   // stage X (bf16 direct)
            const unsigned short* src = xcb + (size_t)(r0 + xrow) * C_ + kc + xhalf * 32;
            unsigned short* drow = tX + xrow * 64;
            #pragma unroll
            for (int i = 0; i < 4; ++i) {
                uint4 v = *(const uint4*)(src + i * 8);
                int g = xhalf * 4 + i;
                *(uint4*)&drow[(g ^ (xrow & 7)) * 8] = v;
            }
        }
        {   // stage W (f32 -> bf16)
            const float* srcw = w + ((size_t)o * H_ + h0 + wr) * C_ + kc + wq * 16;
            unsigned short* drow = tW + wr * 64;
            #pragma unroll
            for (int i = 0; i < 2; ++i) {
                float4 v0 = *(const float4*)(srcw + i * 8);
                float4 v1 = *(const float4*)(srcw + i * 8 + 4);
                uint4 pk;
                pk.x = packbf2(v0.x, v0.y); pk.y = packbf2(v0.z, v0.w);
                pk.z = packbf2(v1.x, v1.y); pk.w = packbf2(v1.z, v1.w);
                int g = wq * 2 + i;
                *(uint4*)&drow[(g ^ (wr & 7)) * 8] = pk;
            }
        }
        __syncthreads();
        #pragma unroll
        for (int kk = 0; kk < 64; kk += 32) {
            short8 af[4], bf2[2];
            #pragma unroll
            for (int fi = 0; fi < 4; ++fi)
                af[fi] = *(const short8*)&tX[(wrow + fi * 16 + lr) * 64 + (gr0 ^ kk)];
            #pragma unroll
            for (int fj = 0; fj < 2; ++fj)
                bf2[fj] = *(const short8*)&tW[(wcol + fj * 16 + lr) * 64 + (gr0 ^ kk)];
            #pragma unroll
            for (int fi = 0; fi < 4; ++fi)
                #pragma unroll
                for (int fj = 0; fj < 2; ++fj)
                    acc[fi][fj] = __builtin_amdgcn_mfma_f32_16x16x32_bf16(
                        af[fi], bf2[fj], acc[fi][fj], 0, 0, 0);
        }
    }
    #pragma unroll
    for (int fi = 0; fi < 4; ++fi)
        #pragma unroll
        for (int rr = 0; rr < 4; ++rr) {
            int r = r0 + wrow + fi * 16 + lq * 4 + rr;
            #pragma unroll
            for (int fj = 0; fj < 2; ++fj) {
                int h = h0 + wcol + fj * 16 + lr;
                int hj = (h < HALF_) ? h : (h - HALF_);
                int sel = (h < HALF_) ? 0 : 1;
                xh[(size_t)r * H_ + hj * 2 + sel] = acc[fi][fj][rr] + bias[o * H_ + h];
            }
        }
}

// ---------------- A2a: inv-freq table (fp64) ----------------
__global__ void init_invf(double* __restrict__ invf) {
    int j = threadIdx.x;
    if (j < HALF_) invf[j] = exp2(-20.0 * (double)j / 384.0);
}

// ---------------- A2b: RoPE cos/sin table, interleaved {c,s} f32 ----------------
__global__ void rope_table(const int* __restrict__ sp,
                           const double* __restrict__ invf,
                           float2* __restrict__ csf) {
    int e = blockIdx.x * blockDim.x + threadIdx.x;  // 1024*384
    if (e >= B_ * 4 * P_ * HALF_) return;
    int j = e % HALF_;
    int r = e / HALF_;
    int s = sp[r];
    const double TWO_PI = 6.283185307179586476925286766559;
    double ang = (double)s * invf[j];
    double k = rint(ang * (1.0 / TWO_PI));
    float fr = (float)(ang - k * TWO_PI);
    float sv, cv;
    __sincosf(fr, &sv, &cv);
    csf[e] = make_float2(cv, sv);
}

// ---------------- B: junction GEMM via bf16 MFMA ----------------
// block = one (b,sign,t), 512 thr = 8 waves, each 64x32 of 128x128 out.
// K=768 as 12 chunks of 64 k (32 pairs). SINGLE 32KB LDS buffer (128B rows,
// 2-way-free swizzle), 2 barriers/chunk.
// __launch_bounds__(512,4): VGPR cap 128. Live state = ~52 VGPR + 32 AGPR
// (unified file on gfx950) = 84; caps of 85 (bound 6) or 64 (bound 8) SPILL
// (R6: 1.6GB scratch writes; R7: 410MB). Bound 4 is the no-spill maximum;
// occupancy then = min(LDS 4, VGPR 512/84 -> 6 waves/SIMD) = 3 blocks/CU.
__global__ __launch_bounds__(512, 4) void junction_mfma(
    const float* __restrict__ xh, const float* __restrict__ csf,
    const float* __restrict__ rpd, const float* __restrict__ rpa,
    const float* __restrict__ rnd, const float* __restrict__ rna,
    const int* __restrict__ org, const int* __restrict__ sp,
    unsigned short* __restrict__ w1) {
    __shared__ __align__(16) unsigned short smem[16384];  // 32KB: tD | tA, 128x64 each
    __shared__ int vD[P_], vA[P_];
    unsigned short* tD = smem;          // rows of 64 ushorts = 128B
    unsigned short* tA = smem + 8192;

    // bijective XCD swizzle (nwg = 1468, nwg%8 = 4)
    int nwg = gridDim.x;
    int orig = blockIdx.x;
    int xcd = orig & 7;
    int q = nwg >> 3, r8 = nwg & 7;
    int blk = (xcd < r8 ? xcd * (q + 1) : r8 * (q + 1) + (xcd - r8) * q) + (orig >> 3);

    int t = blk % T_;
    int sign = (blk / T_) & 1;
    int b = blk / (2 * T_);
    int o = org[b];
    int gd = sign * 2, ga = sign * 2 + 1;
    const float* pd = sign ? rnd : rpd;
    const float* pa = sign ? rna : rpa;
    int tid = threadIdx.x;

    const float* sc_d = pd + ((size_t)(o * 2 + 0) * T_ + t) * H_;
    const float* of_d = pd + ((size_t)(o * 2 + 1) * T_ + t) * H_;
    const float* sc_a = pa + ((size_t)(o * 2 + 0) * T_ + t) * H_;
    const float* of_a = pa + ((size_t)(o * 2 + 1) * T_ + t) * H_;

    if (tid < P_) {
        vD[tid] = sp[(b * 4 + gd) * P_ + tid] >= 0;
        vA[tid] = sp[(b * 4 + ga) * P_ + tid] >= 0;
    }
    const float* xd = xh + ((size_t)(b * 4 + gd) * P_) * H_;   // interleaved {x1,x2}
    const float* xa = xh + ((size_t)(b * 4 + ga) * P_) * H_;
    const float* cd = csf + ((size_t)(b * 4 + gd) * P_) * H_;  // interleaved {c,s}
    const float* ca = csf + ((size_t)(b * 4 + ga) * P_) * H_;

    int lane = tid & 63, wid = tid >> 6;
    int wrow = (wid >> 2) * 64, wcol = (wid & 3) * 32;
    int lr = lane & 15, lq = lane >> 4;
    int gr0 = (lq ^ (lr & 7)) * 8;     // read granule within 64-ushort row

    f32x4 acc[4][2];
    #pragma unroll
    for (int i = 0; i < 4; ++i)
        #pragma unroll
        for (int j = 0; j < 2; ++j) acc[i][j] = (f32x4){0.f, 0.f, 0.f, 0.f};

    int jp = tid & 15;        // pairs {2jp, 2jp+1} of the 32-pair chunk
    int prow = tid >> 4;      // 0..31; p = pass*32 + prow, 4 passes

    for (int ch = 0; ch < 12; ++ch) {
        int jb = ch * 32 + 2 * jp;
        // per-chunk coefs (8B loads, broadcast-shared across prow)
        f32x2 s1d = *(const f32x2*)(sc_d + jb);
        f32x2 o1d = *(const f32x2*)(of_d + jb);
        f32x2 s2d = *(const f32x2*)(sc_d + jb + HALF_);
        f32x2 o2d = *(const f32x2*)(of_d + jb + HALF_);
        f32x2 s1a = *(const f32x2*)(sc_a + jb);
        f32x2 o1a = *(const f32x2*)(of_a + jb);
        f32x2 s2a = *(const f32x2*)(sc_a + jb + HALF_);
        f32x2 o2a = *(const f32x2*)(of_a + jb + HALF_);

        if (ch) __syncthreads();   // all MFMA(ch-1) reads done -> safe to overwrite

        #pragma unroll
        for (int pass = 0; pass < 4; ++pass) {
            int p = pass * 32 + prow;
            int sw = p * 64 + (((jp >> 1) ^ (p & 7)) << 3) + ((jp & 1) << 2);
            {   // donor
                float4 xv = *(const float4*)(xd + p * H_ + 2 * jb); // x1[j],x2[j],x1[j+1],x2[j+1]
                float4 cv = *(const float4*)(cd + p * H_ + 2 * jb); // c[j],s[j],c[j+1],s[j+1]
                float u1 = fmaf(s1d.x, xv.x, o1d.x);
                float u2 = fmaf(s2d.x, xv.y, o2d.x);
                float r1 = u1 * cv.x - u2 * cv.y;
                float r2 = u1 * cv.y + u2 * cv.x;
                float u3 = fmaf(s1d.y, xv.z, o1d.y);
                float u4 = fmaf(s2d.y, xv.w, o2d.y);
                float r3 = u3 * cv.z - u4 * cv.w;
                float r4 = u3 * cv.w + u4 * cv.z;
                uint2 wv;
                wv.x = packbf2(r1, r2);
                wv.y = packbf2(r3, r4);
                *(uint2*)&tD[sw] = wv;
            }
            {   // acceptor
                float4 xv = *(const float4*)(xa + p * H_ + 2 * jb);
                float4 cv = *(const float4*)(ca + p * H_ + 2 * jb);
                float u1 = fmaf(s1a.x, xv.x, o1a.x);
                float u2 = fmaf(s2a.x, xv.y, o2a.x);
                float r1 = u1 * cv.x - u2 * cv.y;
                float r2 = u1 * cv.y + u2 * cv.x;
                float u3 = fmaf(s1a.y, xv.z, o1a.y);
                float u4 = fmaf(s2a.y, xv.w, o2a.y);
                float r3 = u3 * cv.z - u4 * cv.w;
                float r4 = u3 * cv.w + u4 * cv.z;
                uint2 wv;
                wv.x = packbf2(r1, r2);
                wv.y = packbf2(r3, r4);
                *(uint2*)&tA[sw] = wv;
            }
        }
        __syncthreads();

        __builtin_amdgcn_s_setprio(1);
        #pragma unroll
        for (int kk = 0; kk < 64; kk += 32) {
            short8 af[4], bf2[2];
            #pragma unroll
            for (int fi = 0; fi < 4; ++fi)
                af[fi] = *(const short8*)&tD[(wrow + fi * 16 + lr) * 64 + (gr0 ^ kk)];
            #pragma unroll
            for (int fj = 0; fj < 2; ++fj)
                bf2[fj] = *(const short8*)&tA[(wcol + fj * 16 + lr) * 64 + (gr0 ^ kk)];
            #pragma unroll
            for (int fi = 0; fi < 4; ++fi)
                #pragma unroll
                for (int fj = 0; fj < 2; ++fj)
                    acc[fi][fj] = __builtin_amdgcn_mfma_f32_16x16x32_bf16(
                        af[fi], bf2[fj], acc[fi][fj], 0, 0, 0);
        }
        __builtin_amdgcn_s_setprio(0);
    }

    // ---- epilogue: softplus+mask -> bf16 LDS stage (32KB) -> coalesced copy ----
    __syncthreads();               // all MFMA reads of smem done before restage
    #pragma unroll
    for (int fi = 0; fi < 4; ++fi) {
        #pragma unroll
        for (int rr = 0; rr < 4; ++rr) {
            int d = wrow + fi * 16 + lq * 4 + rr;
            int vd = vD[d];
            #pragma unroll
            for (int fj = 0; fj < 2; ++fj) {
                int a = wcol + fj * 16 + lr;
                float x = acc[fi][fj][rr];
                float v = 0.0f;
                if (vd && vA[a]) v = (x > 15.0f) ? x : log1pf(__expf(x));
                smem[d * P_ + a] = packbf1(v);
            }
        }
    }
    __syncthreads();
    const uint4* src4 = (const uint4*)smem;                       // 2048 uint4
    uint4* dst4 = (uint4*)(w1 + ((size_t)((b * 2 + sign) * T_ + t) * P_) * P_);
    for (int i = tid; i < 2048; i += 512) dst4[i] = src4[i];
}

// ---------------- C: transpose bf16 [b][sign][t][d][a] -> f32 [b][d][a][sign*T+t] ----------------
__global__ __launch_bounds__(256) void transpose_out(const __hip_bfloat16* __restrict__ w1,
                                                     float* __restrict__ pred) {
    __shared__ float tile[64 * 129];
    int blk = blockIdx.x;            // bs*128*6 + d*6 + tt   (3072 blocks)
    int tt = blk % 6;
    int d = (blk / 6) % P_;
    int bs = blk / (6 * P_);         // b*2+sign
    int b = bs >> 1, sign = bs & 1;
    int t0 = tt * 64;
    int tcnt = min(64, T_ - t0);
    int tid = threadIdx.x;

    const __hip_bfloat16* src = w1 + (size_t)bs * T_ * P_ * P_ + (size_t)d * P_;
    for (int e = tid; e < tcnt * P_; e += 256) {
        int i = e >> 7, a = e & 127;
        tile[i * 129 + a] = __bfloat162float(src[(size_t)(t0 + i) * P_ * P_ + a]);
    }
    __syncthreads();
    float* dst = pred + ((size_t)(b * P_ + d) * P_) * TT_ + sign * T_ + t0;
    for (int e = tid; e < P_ * 64; e += 256) {
        int a = e >> 6, ii = e & 63;
        if (ii < tcnt) dst[(size_t)a * TT_ + ii] = tile[ii * 129 + a];
    }
}

// ---------------- D: mask fill ----------------
__global__ void mask_fill(const int* __restrict__ sp, float* __restrict__ mask) {
    int blk = blockIdx.x;            // (b*128+d)*128+a   (32768 blocks)
    int a = blk & 127;
    int d = (blk >> 7) & 127;
    int b = blk >> 14;
    bool vp = (sp[(b * 4 + 0) * P_ + d] >= 0) && (sp[(b * 4 + 1) * P_ + a] >= 0);
    bool vn = (sp[(b * 4 + 2) * P_ + d] >= 0) && (sp[(b * 4 + 3) * P_ + a] >= 0);
    float* dst = mask + (size_t)blk * TT_;
    for (int st = threadIdx.x; st < TT_; st += blockDim.x)
        dst[st] = (st < T_ ? vp : vn) ? 1.0f : 0.0f;
}

extern "C" void kernel_launch(void* const* d_in, const int* in_sizes, int n_in,
                              void* d_out, int out_size, void* d_ws, size_t ws_size,
                              hipStream_t stream) {
    const float* emb  = (const float*)d_in[0];
    const float* w    = (const float*)d_in[1];
    const float* bias = (const float*)d_in[2];
    const float* rpd  = (const float*)d_in[3];
    const float* rpa  = (const float*)d_in[4];
    const float* rnd  = (const float*)d_in[5];
    const float* rna  = (const float*)d_in[6];
    const int*   org  = (const int*)d_in[7];
    const int*   sp   = (const int*)d_in[8];

    float* out = (float*)d_out;
    float* ws  = (float*)d_ws;
    float* xh   = ws + XH_OFF;
    float* csf  = ws + CSF_OFF;
    double* invf = (double*)(ws + INVF_OFF);
    unsigned short* xcb = (unsigned short*)(ws + XCB_OFF);
    float* pred  = out;
    float* maskp = out + PRED_ELEMS;
    unsigned short* w1 = (unsigned short*)maskp;   // bf16 staging in mask half

    init_invf<<<1, 384, 0, stream>>>(invf);
    gather_cols<<<1024, 256, 0, stream>>>(emb, sp, xcb);
    rope_table<<<1536, 256, 0, stream>>>(sp, invf, (float2*)csf);
    dim3 gl(8, 12);
    logits_mfma<<<gl, 256, 0, stream>>>(xcb, w, bias, org, xh);
    junction_mfma<<<2 * 2 * T_, 512, 0, stream>>>(xh, csf, rpd, rpa, rnd, rna, org, sp, w1);
    transpose_out<<<2 * 2 * P_ * 6, 256, 0, stream>>>((const __hip_bfloat16*)w1, pred);
    mask_fill<<<32768, 256, 0, stream>>>(sp, maskp);
}

// Round 9
// 314.662 us; speedup vs baseline: 2.6408x; 1.1147x over previous
//
#include <hip/hip_runtime.h>
#include <hip/hip_bf16.h>
#include <math.h>
#include <string.h>

#define B_    2
#define C_    1536
#define S_    16384
#define H_    768
#define T_    367
#define P_    128
#define HALF_ 384
#define TT_   734                 // 2*T
#define PRED_ELEMS 24051712      // B*P*P*2T

// ws layout (float slots)
#define XH_OFF   0               // [B*4*P][HALF][2] f32 interleaved {x1,x2}  786,432
#define CSF_OFF  786432          // [B*4*P][HALF][2] f32 interleaved {c,s}    786,432
#define INVF_OFF 1572864         // 384 doubles (768 slots)
#define XCB_OFF  1573632         // [B*4*P][C] bf16  (393,216 slots)

typedef short short8 __attribute__((ext_vector_type(8)));
typedef float f32x4  __attribute__((ext_vector_type(4)));

__device__ __forceinline__ unsigned int packbf2(float a, float b) {
    __hip_bfloat162 h = __float22bfloat162_rn(make_float2(a, b));
    unsigned int r; __builtin_memcpy(&r, &h, 4); return r;
}
__device__ __forceinline__ unsigned short packbf1(float a) {
    __hip_bfloat16 h = __float2bfloat16(a);
    unsigned short r; __builtin_memcpy(&r, &h, 2); return r;
}

// ---------------- A0: gather embedding columns -> bf16 ----------------
__global__ void gather_cols(const float* __restrict__ emb,
                            const int* __restrict__ sp,
                            unsigned short* __restrict__ xcb) {
    int blk = blockIdx.x;           // B*4*P = 1024
    int p = blk & 127;
    int g = (blk >> 7) & 3;
    int b = blk >> 9;
    int s = sp[(b * 4 + g) * P_ + p];
    const float* src = emb + (size_t)b * C_ * S_ + s;
    unsigned short* dst = xcb + ((size_t)(b * 4 + g) * P_ + p) * C_;
    for (int c = threadIdx.x; c < C_; c += blockDim.x)
        dst[c] = packbf1(src[(size_t)c * S_]);
}

// ---------------- A1: gathered-logits GEMM via bf16 MFMA, 64x64 tiles ----------------
// grid (16,12) = 192 blocks; 256 thr = 4 waves (2x2), wave = 32x32 out.
// writes xh interleaved: xh[r][hj*2 + (h>=384)]
__global__ __launch_bounds__(256) void logits_mfma(
    const unsigned short* __restrict__ xcb, const float* __restrict__ w,
    const float* __restrict__ bias, const int* __restrict__ org,
    float* __restrict__ xh) {
    __shared__ __align__(16) unsigned short tX[64 * 64];   // 8KB
    __shared__ __align__(16) unsigned short tW[64 * 64];   // 8KB
    int mt = blockIdx.x;             // 0..15 (rows of 64)
    int nt = blockIdx.y;             // 0..11 (cols of 64)
    int o = org[mt >> 3];
    int r0 = mt * 64, h0 = nt * 64;
    int tid = threadIdx.x;
    int lane = tid & 63, wid = tid >> 6;
    int wrow = (wid >> 1) * 32, wcol = (wid & 1) * 32;
    int lr = lane & 15, lq = lane >> 4;
    int gr0 = (lq ^ (lr & 7)) * 8;

    f32x4 acc[2][2];
    #pragma unroll
    for (int i = 0; i < 2; ++i)
        #pragma unroll
        for (int j = 0; j < 2; ++j) acc[i][j] = (f32x4){0.f, 0.f, 0.f, 0.f};

    int srow = tid >> 2, sg = tid & 3;   // staging: 4 thr/row, 2 granules each

    for (int kc = 0; kc < C_; kc += 64) {
        if (kc) __syncthreads();
        {   // stage X (bf16 direct): row srow, granules sg, sg+4
            const unsigned short* src = xcb + (size_t)(r0 + srow) * C_ + kc;
            unsigned short* drow = tX + srow * 64;
            #pragma unroll
            for (int i = 0; i < 2; ++i) {
                int g = sg + i * 4;
                uint4 v = *(const uint4*)(src + g * 8);
                *(uint4*)&drow[(g ^ (srow & 7)) * 8] = v;
            }
        }
        {   // stage W (f32 -> bf16)
            const float* srcw = w + ((size_t)o * H_ + h0 + srow) * C_ + kc;
            unsigned short* drow = tW + srow * 64;
            #pragma unroll
            for (int i = 0; i < 2; ++i) {
                int g = sg + i * 4;
                float4 v0 = *(const float4*)(srcw + g * 8);
                float4 v1 = *(const float4*)(srcw + g * 8 + 4);
                uint4 pk;
                pk.x = packbf2(v0.x, v0.y); pk.y = packbf2(v0.z, v0.w);
                pk.z = packbf2(v1.x, v1.y); pk.w = packbf2(v1.z, v1.w);
                *(uint4*)&drow[(g ^ (srow & 7)) * 8] = pk;
            }
        }
        __syncthreads();
        #pragma unroll
        for (int kk = 0; kk < 64; kk += 32) {
            short8 af[2], bf2[2];
            #pragma unroll
            for (int fi = 0; fi < 2; ++fi)
                af[fi] = *(const short8*)&tX[(wrow + fi * 16 + lr) * 64 + (gr0 ^ kk)];
            #pragma unroll
            for (int fj = 0; fj < 2; ++fj)
                bf2[fj] = *(const short8*)&tW[(wcol + fj * 16 + lr) * 64 + (gr0 ^ kk)];
            #pragma unroll
            for (int fi = 0; fi < 2; ++fi)
                #pragma unroll
                for (int fj = 0; fj < 2; ++fj)
                    acc[fi][fj] = __builtin_amdgcn_mfma_f32_16x16x32_bf16(
                        af[fi], bf2[fj], acc[fi][fj], 0, 0, 0);
        }
    }
    #pragma unroll
    for (int fi = 0; fi < 2; ++fi)
        #pragma unroll
        for (int rr = 0; rr < 4; ++rr) {
            int r = r0 + wrow + fi * 16 + lq * 4 + rr;
            #pragma unroll
            for (int fj = 0; fj < 2; ++fj) {
                int h = h0 + wcol + fj * 16 + lr;
                int hj = (h < HALF_) ? h : (h - HALF_);
                int sel = (h < HALF_) ? 0 : 1;
                xh[(size_t)r * H_ + hj * 2 + sel] = acc[fi][fj][rr] + bias[o * H_ + h];
            }
        }
}

// ---------------- A2a: inv-freq table (fp64) ----------------
__global__ void init_invf(double* __restrict__ invf) {
    int j = threadIdx.x;
    if (j < HALF_) invf[j] = exp2(-20.0 * (double)j / 384.0);
}

// ---------------- A2b: RoPE cos/sin table, interleaved {c,s} f32 ----------------
__global__ void rope_table(const int* __restrict__ sp,
                           const double* __restrict__ invf,
                           float2* __restrict__ csf) {
    int e = blockIdx.x * blockDim.x + threadIdx.x;  // 1024*384
    if (e >= B_ * 4 * P_ * HALF_) return;
    int j = e % HALF_;
    int r = e / HALF_;
    int s = sp[r];
    const double TWO_PI = 6.283185307179586476925286766559;
    double ang = (double)s * invf[j];
    double k = rint(ang * (1.0 / TWO_PI));
    float fr = (float)(ang - k * TWO_PI);
    float sv, cv;
    __sincosf(fr, &sv, &cv);
    csf[e] = make_float2(cv, sv);
}

// ---------------- B: junction GEMM via bf16 MFMA ----------------
// block = one (b,sign,t), 512 thr = 8 waves, each 64x32 of 128x128 out.
// K=768 as 12 chunks of 64 k (32 pairs). Coefs staged ONCE in LDS (12KB).
// Build: thread owns 4 pairs (one 16B granule) x 2 p-rows -> ds_write_b128.
// Single 32KB tile buffer, 2 barriers/chunk. (512,4): no spill (R6/R7 lesson:
// live ~80 VGPR + 32 AGPR unified; caps <128 spill catastrophically).
__global__ __launch_bounds__(512, 4) void junction_mfma(
    const float* __restrict__ xh, const float* __restrict__ csf,
    const float* __restrict__ rpd, const float* __restrict__ rpa,
    const float* __restrict__ rnd, const float* __restrict__ rna,
    const int* __restrict__ org, const int* __restrict__ sp,
    unsigned short* __restrict__ w1) {
    __shared__ __align__(16) unsigned short smem[16384];  // 32KB: tD | tA, 128x64 each
    __shared__ __align__(16) float scof[4 * H_];          // 12KB: scD|ofD|scA|ofA
    __shared__ int vD[P_], vA[P_];
    unsigned short* tD = smem;          // rows of 64 ushorts = 128B
    unsigned short* tA = smem + 8192;

    // bijective XCD swizzle (nwg = 1468, nwg%8 = 4)
    int nwg = gridDim.x;
    int orig = blockIdx.x;
    int xcd = orig & 7;
    int q = nwg >> 3, r8 = nwg & 7;
    int blk = (xcd < r8 ? xcd * (q + 1) : r8 * (q + 1) + (xcd - r8) * q) + (orig >> 3);

    int t = blk % T_;
    int sign = (blk / T_) & 1;
    int b = blk / (2 * T_);
    int o = org[b];
    int gd = sign * 2, ga = sign * 2 + 1;
    const float* pd = sign ? rnd : rpd;
    const float* pa = sign ? rna : rpa;
    int tid = threadIdx.x;

    const float* sc_d = pd + ((size_t)(o * 2 + 0) * T_ + t) * H_;
    const float* of_d = pd + ((size_t)(o * 2 + 1) * T_ + t) * H_;
    const float* sc_a = pa + ((size_t)(o * 2 + 0) * T_ + t) * H_;
    const float* of_a = pa + ((size_t)(o * 2 + 1) * T_ + t) * H_;
    // stage all coefs once (4 x 768 f32)
    for (int e = tid; e < H_; e += 512) {
        scof[e]           = sc_d[e];
        scof[H_ + e]      = of_d[e];
        scof[2 * H_ + e]  = sc_a[e];
        scof[3 * H_ + e]  = of_a[e];
    }
    if (tid < P_) {
        vD[tid] = sp[(b * 4 + gd) * P_ + tid] >= 0;
        vA[tid] = sp[(b * 4 + ga) * P_ + tid] >= 0;
    }
    const float* xd = xh + ((size_t)(b * 4 + gd) * P_) * H_;   // interleaved {x1,x2}
    const float* xa = xh + ((size_t)(b * 4 + ga) * P_) * H_;
    const float* cd = csf + ((size_t)(b * 4 + gd) * P_) * H_;  // interleaved {c,s}
    const float* ca = csf + ((size_t)(b * 4 + ga) * P_) * H_;

    int lane = tid & 63, wid = tid >> 6;
    int wrow = (wid >> 2) * 64, wcol = (wid & 3) * 32;
    int lr = lane & 15, lq = lane >> 4;
    int gr0 = (lq ^ (lr & 7)) * 8;     // read granule within 64-ushort row

    f32x4 acc[4][2];
    #pragma unroll
    for (int i = 0; i < 4; ++i)
        #pragma unroll
        for (int j = 0; j < 2; ++j) acc[i][j] = (f32x4){0.f, 0.f, 0.f, 0.f};

    int jp = tid & 7;         // granule: pairs {4jp..4jp+3} of the 32-pair chunk
    int prow = tid >> 3;      // 0..63; p = pass*64 + prow, 2 passes
    int swc = ((jp ^ (prow & 7)) << 3);  // pass-invariant swizzled granule offset

    __syncthreads();          // scof / vD / vA ready

    for (int ch = 0; ch < 12; ++ch) {
        int jb4 = ch * 32 + 4 * jp;    // first pair (j index) of this thread's granule
        // coef reads from LDS (b128, broadcast across prow groups)
        float4 s1d = *(const float4*)&scof[jb4];
        float4 o1d = *(const float4*)&scof[H_ + jb4];
        float4 s2d = *(const float4*)&scof[jb4 + HALF_];
        float4 o2d = *(const float4*)&scof[H_ + jb4 + HALF_];
        float4 s1a = *(const float4*)&scof[2 * H_ + jb4];
        float4 o1a = *(const float4*)&scof[3 * H_ + jb4];
        float4 s2a = *(const float4*)&scof[2 * H_ + jb4 + HALF_];
        float4 o2a = *(const float4*)&scof[3 * H_ + jb4 + HALF_];

        if (ch) __syncthreads();   // all MFMA(ch-1) reads done -> safe to overwrite

        #pragma unroll
        for (int pass = 0; pass < 2; ++pass) {
            int p = pass * 64 + prow;
            int sw = p * 64 + swc;
            {   // donor: 4 pairs -> 8 bf16 -> one b128 write
                float4 xv0 = *(const float4*)(xd + p * H_ + 2 * jb4);
                float4 xv1 = *(const float4*)(xd + p * H_ + 2 * jb4 + 4);
                float4 cv0 = *(const float4*)(cd + p * H_ + 2 * jb4);
                float4 cv1 = *(const float4*)(cd + p * H_ + 2 * jb4 + 4);
                float u1, u2;
                uint4 wv;
                u1 = fmaf(s1d.x, xv0.x, o1d.x); u2 = fmaf(s2d.x, xv0.y, o2d.x);
                wv.x = packbf2(u1 * cv0.x - u2 * cv0.y, u1 * cv0.y + u2 * cv0.x);
                u1 = fmaf(s1d.y, xv0.z, o1d.y); u2 = fmaf(s2d.y, xv0.w, o2d.y);
                wv.y = packbf2(u1 * cv0.z - u2 * cv0.w, u1 * cv0.w + u2 * cv0.z);
                u1 = fmaf(s1d.z, xv1.x, o1d.z); u2 = fmaf(s2d.z, xv1.y, o2d.z);
                wv.z = packbf2(u1 * cv1.x - u2 * cv1.y, u1 * cv1.y + u2 * cv1.x);
                u1 = fmaf(s1d.w, xv1.z, o1d.w); u2 = fmaf(s2d.w, xv1.w, o2d.w);
                wv.w = packbf2(u1 * cv1.z - u2 * cv1.w, u1 * cv1.w + u2 * cv1.z);
                *(uint4*)&tD[sw] = wv;
            }
            {   // acceptor
                float4 xv0 = *(const float4*)(xa + p * H_ + 2 * jb4);
                float4 xv1 = *(const float4*)(xa + p * H_ + 2 * jb4 + 4);
                float4 cv0 = *(const float4*)(ca + p * H_ + 2 * jb4);
                float4 cv1 = *(const float4*)(ca + p * H_ + 2 * jb4 + 4);
                float u1, u2;
                uint4 wv;
                u1 = fmaf(s1a.x, xv0.x, o1a.x); u2 = fmaf(s2a.x, xv0.y, o2a.x);
                wv.x = packbf2(u1 * cv0.x - u2 * cv0.y, u1 * cv0.y + u2 * cv0.x);
                u1 = fmaf(s1a.y, xv0.z, o1a.y); u2 = fmaf(s2a.y, xv0.w, o2a.y);
                wv.y = packbf2(u1 * cv0.z - u2 * cv0.w, u1 * cv0.w + u2 * cv0.z);
                u1 = fmaf(s1a.z, xv1.x, o1a.z); u2 = fmaf(s2a.z, xv1.y, o2a.z);
                wv.z = packbf2(u1 * cv1.x - u2 * cv1.y, u1 * cv1.y + u2 * cv1.x);
                u1 = fmaf(s1a.w, xv1.z, o1a.w); u2 = fmaf(s2a.w, xv1.w, o2a.w);
                wv.w = packbf2(u1 * cv1.z - u2 * cv1.w, u1 * cv1.w + u2 * cv1.z);
                *(uint4*)&tA[sw] = wv;
            }
        }
        __syncthreads();

        __builtin_amdgcn_s_setprio(1);
        #pragma unroll
        for (int kk = 0; kk < 64; kk += 32) {
            short8 af[4], bf2[2];
            #pragma unroll
            for (int fi = 0; fi < 4; ++fi)
                af[fi] = *(const short8*)&tD[(wrow + fi * 16 + lr) * 64 + (gr0 ^ kk)];
            #pragma unroll
            for (int fj = 0; fj < 2; ++fj)
                bf2[fj] = *(const short8*)&tA[(wcol + fj * 16 + lr) * 64 + (gr0 ^ kk)];
            #pragma unroll
            for (int fi = 0; fi < 4; ++fi)
                #pragma unroll
                for (int fj = 0; fj < 2; ++fj)
                    acc[fi][fj] = __builtin_amdgcn_mfma_f32_16x16x32_bf16(
                        af[fi], bf2[fj], acc[fi][fj], 0, 0, 0);
        }
        __builtin_amdgcn_s_setprio(0);
    }

    // ---- epilogue: softplus+mask -> bf16 LDS stage (32KB) -> coalesced copy ----
    __syncthreads();               // all MFMA reads of smem done before restage
    #pragma unroll
    for (int fi = 0; fi < 4; ++fi) {
        #pragma unroll
        for (int rr = 0; rr < 4; ++rr) {
            int d = wrow + fi * 16 + lq * 4 + rr;
            int vd = vD[d];
            #pragma unroll
            for (int fj = 0; fj < 2; ++fj) {
                int a = wcol + fj * 16 + lr;
                float x = acc[fi][fj][rr];
                float v = 0.0f;
                if (vd && vA[a]) v = (x > 15.0f) ? x : __logf(1.0f + __expf(x));
                smem[d * P_ + a] = packbf1(v);
            }
        }
    }
    __syncthreads();
    const uint4* src4 = (const uint4*)smem;                       // 2048 uint4
    uint4* dst4 = (uint4*)(w1 + ((size_t)((b * 2 + sign) * T_ + t) * P_) * P_);
    for (int i = tid; i < 2048; i += 512) dst4[i] = src4[i];
}

// ---------------- C: transpose bf16 [b][sign][t][d][a] -> f32 [b][d][a][sign*T+t] ----------------
__global__ __launch_bounds__(256) void transpose_out(const __hip_bfloat16* __restrict__ w1,
                                                     float* __restrict__ pred) {
    __shared__ float tile[64 * 129];
    int blk = blockIdx.x;            // bs*128*6 + d*6 + tt   (3072 blocks)
    int tt = blk % 6;
    int d = (blk / 6) % P_;
    int bs = blk / (6 * P_);         // b*2+sign
    int b = bs >> 1, sign = bs & 1;
    int t0 = tt * 64;
    int tcnt = min(64, T_ - t0);
    int tid = threadIdx.x;

    const __hip_bfloat16* src = w1 + (size_t)bs * T_ * P_ * P_ + (size_t)d * P_;
    for (int e = tid; e < tcnt * P_; e += 256) {
        int i = e >> 7, a = e & 127;
        tile[i * 129 + a] = __bfloat162float(src[(size_t)(t0 + i) * P_ * P_ + a]);
    }
    __syncthreads();
    float* dst = pred + ((size_t)(b * P_ + d) * P_) * TT_ + sign * T_ + t0;
    for (int e = tid; e < P_ * 64; e += 256) {
        int a = e >> 6, ii = e & 63;
        if (ii < tcnt) dst[(size_t)a * TT_ + ii] = tile[ii * 129 + a];
    }
}

// ---------------- D: mask fill ----------------
__global__ void mask_fill(const int* __restrict__ sp, float* __restrict__ mask) {
    int blk = blockIdx.x;            // (b*128+d)*128+a   (32768 blocks)
    int a = blk & 127;
    int d = (blk >> 7) & 127;
    int b = blk >> 14;
    bool vp = (sp[(b * 4 + 0) * P_ + d] >= 0) && (sp[(b * 4 + 1) * P_ + a] >= 0);
    bool vn = (sp[(b * 4 + 2) * P_ + d] >= 0) && (sp[(b * 4 + 3) * P_ + a] >= 0);
    float* dst = mask + (size_t)blk * TT_;
    for (int st = threadIdx.x; st < TT_; st += blockDim.x)
        dst[st] = (st < T_ ? vp : vn) ? 1.0f : 0.0f;
}

extern "C" void kernel_launch(void* const* d_in, const int* in_sizes, int n_in,
                              void* d_out, int out_size, void* d_ws, size_t ws_size,
                              hipStream_t stream) {
    const float* emb  = (const float*)d_in[0];
    const float* w    = (const float*)d_in[1];
    const float* bias = (const float*)d_in[2];
    const float* rpd  = (const float*)d_in[3];
    const float* rpa  = (const float*)d_in[4];
    const float* rnd  = (const float*)d_in[5];
    const float* rna  = (const float*)d_in[6];
    const int*   org  = (const int*)d_in[7];
    const int*   sp   = (const int*)d_in[8];

    float* out = (float*)d_out;
    float* ws  = (float*)d_ws;
    float* xh   = ws + XH_OFF;
    float* csf  = ws + CSF_OFF;
    double* invf = (double*)(ws + INVF_OFF);
    unsigned short* xcb = (unsigned short*)(ws + XCB_OFF);
    float* pred  = out;
    float* maskp = out + PRED_ELEMS;
    unsigned short* w1 = (unsigned short*)maskp;   // bf16 staging in mask half

    init_invf<<<1, 384, 0, stream>>>(invf);
    gather_cols<<<1024, 256, 0, stream>>>(emb, sp, xcb);
    rope_table<<<1536, 256, 0, stream>>>(sp, invf, (float2*)csf);
    dim3 gl(16, 12);
    logits_mfma<<<gl, 256, 0, stream>>>(xcb, w, bias, org, xh);
    junction_mfma<<<2 * 2 * T_, 512, 0, stream>>>(xh, csf, rpd, rpa, rnd, rna, org, sp, w1);
    transpose_out<<<2 * 2 * P_ * 6, 256, 0, stream>>>((const __hip_bfloat16*)w1, pred);
    mask_fill<<<32768, 256, 0, stream>>>(sp, maskp);
}

// Round 10
// 269.928 us; speedup vs baseline: 3.0784x; 1.1657x over previous
//
#include <hip/hip_runtime.h>
#include <hip/hip_bf16.h>
#include <math.h>
#include <string.h>

#define B_    2
#define C_    1536
#define S_    16384
#define H_    768
#define T_    367
#define P_    128
#define HALF_ 384
#define TT_   734                 // 2*T
#define PRED_ELEMS 24051712      // B*P*P*2T

// ws layout (float slots)
// xh: [r][granule g=hj>>2][ {x1 x4}{x2 x4} ]   (hj = h mod 384, sel = h>=384)
// cs: [r][granule g=j>>2 ][ {c x4}{s x4} ]
#define XH_OFF   0               // 786,432
#define CSF_OFF  786432          // 786,432
#define INVF_OFF 1572864         // 384 doubles (768 slots)
#define XCB_OFF  1573632         // [B*4*P][C] bf16  (393,216 slots)

typedef short short8 __attribute__((ext_vector_type(8)));
typedef float f32x4  __attribute__((ext_vector_type(4)));

__device__ __forceinline__ unsigned int packbf2(float a, float b) {
    __hip_bfloat162 h = __float22bfloat162_rn(make_float2(a, b));
    unsigned int r; __builtin_memcpy(&r, &h, 4); return r;
}
__device__ __forceinline__ unsigned short packbf1(float a) {
    __hip_bfloat16 h = __float2bfloat16(a);
    unsigned short r; __builtin_memcpy(&r, &h, 2); return r;
}

// ---------------- A0: gather embedding columns -> bf16 ----------------
__global__ void gather_cols(const float* __restrict__ emb,
                            const int* __restrict__ sp,
                            unsigned short* __restrict__ xcb) {
    int blk = blockIdx.x;           // B*4*P = 1024
    int p = blk & 127;
    int g = (blk >> 7) & 3;
    int b = blk >> 9;
    int s = sp[(b * 4 + g) * P_ + p];
    const float* src = emb + (size_t)b * C_ * S_ + s;
    unsigned short* dst = xcb + ((size_t)(b * 4 + g) * P_ + p) * C_;
    for (int c = threadIdx.x; c < C_; c += blockDim.x)
        dst[c] = packbf1(src[(size_t)c * S_]);
}

// ---------------- A1: gathered-logits GEMM via bf16 MFMA, 64x64 tiles ----------------
// grid (16,12) = 192 blocks; 256 thr = 4 waves (2x2), wave = 32x32 out.
// writes xh granule-blocked: xh[r][(hj>>2)*8 + (hj&3) + sel*4]
__global__ __launch_bounds__(256) void logits_mfma(
    const unsigned short* __restrict__ xcb, const float* __restrict__ w,
    const float* __restrict__ bias, const int* __restrict__ org,
    float* __restrict__ xh) {
    __shared__ __align__(16) unsigned short tX[64 * 64];   // 8KB
    __shared__ __align__(16) unsigned short tW[64 * 64];   // 8KB
    int mt = blockIdx.x;             // 0..15 (rows of 64)
    int nt = blockIdx.y;             // 0..11 (cols of 64)
    int o = org[mt >> 3];
    int r0 = mt * 64, h0 = nt * 64;
    int tid = threadIdx.x;
    int lane = tid & 63, wid = tid >> 6;
    int wrow = (wid >> 1) * 32, wcol = (wid & 1) * 32;
    int lr = lane & 15, lq = lane >> 4;
    int gr0 = (lq ^ (lr & 7)) * 8;

    f32x4 acc[2][2];
    #pragma unroll
    for (int i = 0; i < 2; ++i)
        #pragma unroll
        for (int j = 0; j < 2; ++j) acc[i][j] = (f32x4){0.f, 0.f, 0.f, 0.f};

    int srow = tid >> 2, sg = tid & 3;   // staging: 4 thr/row, 2 granules each

    for (int kc = 0; kc < C_; kc += 64) {
        if (kc) __syncthreads();
        {   // stage X (bf16 direct): row srow, granules sg, sg+4
            const unsigned short* src = xcb + (size_t)(r0 + srow) * C_ + kc;
            unsigned short* drow = tX + srow * 64;
            #pragma unroll
            for (int i = 0; i < 2; ++i) {
                int g = sg + i * 4;
                uint4 v = *(const uint4*)(src + g * 8);
                *(uint4*)&drow[(g ^ (srow & 7)) * 8] = v;
            }
        }
        {   // stage W (f32 -> bf16)
            const float* srcw = w + ((size_t)o * H_ + h0 + srow) * C_ + kc;
            unsigned short* drow = tW + srow * 64;
            #pragma unroll
            for (int i = 0; i < 2; ++i) {
                int g = sg + i * 4;
                float4 v0 = *(const float4*)(srcw + g * 8);
                float4 v1 = *(const float4*)(srcw + g * 8 + 4);
                uint4 pk;
                pk.x = packbf2(v0.x, v0.y); pk.y = packbf2(v0.z, v0.w);
                pk.z = packbf2(v1.x, v1.y); pk.w = packbf2(v1.z, v1.w);
                *(uint4*)&drow[(g ^ (srow & 7)) * 8] = pk;
            }
        }
        __syncthreads();
        #pragma unroll
        for (int kk = 0; kk < 64; kk += 32) {
            short8 af[2], bf2[2];
            #pragma unroll
            for (int fi = 0; fi < 2; ++fi)
                af[fi] = *(const short8*)&tX[(wrow + fi * 16 + lr) * 64 + (gr0 ^ kk)];
            #pragma unroll
            for (int fj = 0; fj < 2; ++fj)
                bf2[fj] = *(const short8*)&tW[(wcol + fj * 16 + lr) * 64 + (gr0 ^ kk)];
            #pragma unroll
            for (int fi = 0; fi < 2; ++fi)
                #pragma unroll
                for (int fj = 0; fj < 2; ++fj)
                    acc[fi][fj] = __builtin_amdgcn_mfma_f32_16x16x32_bf16(
                        af[fi], bf2[fj], acc[fi][fj], 0, 0, 0);
        }
    }
    #pragma unroll
    for (int fi = 0; fi < 2; ++fi)
        #pragma unroll
        for (int rr = 0; rr < 4; ++rr) {
            int r = r0 + wrow + fi * 16 + lq * 4 + rr;
            #pragma unroll
            for (int fj = 0; fj < 2; ++fj) {
                int h = h0 + wcol + fj * 16 + lr;
                int hj = (h < HALF_) ? h : (h - HALF_);
                int sel = (h < HALF_) ? 0 : 1;
                xh[(size_t)r * H_ + (hj >> 2) * 8 + (hj & 3) + sel * 4] =
                    acc[fi][fj][rr] + bias[o * H_ + h];
            }
        }
}

// ---------------- A2a: inv-freq table (fp64) ----------------
__global__ void init_invf(double* __restrict__ invf) {
    int j = threadIdx.x;
    if (j < HALF_) invf[j] = exp2(-20.0 * (double)j / 384.0);
}

// ---------------- A2b: RoPE cos/sin table, granule-blocked {c x4}{s x4} ----------------
__global__ void rope_table(const int* __restrict__ sp,
                           const double* __restrict__ invf,
                           float* __restrict__ csf) {
    int e = blockIdx.x * blockDim.x + threadIdx.x;  // 1024*384
    if (e >= B_ * 4 * P_ * HALF_) return;
    int j = e % HALF_;
    int r = e / HALF_;
    int s = sp[r];
    const double TWO_PI = 6.283185307179586476925286766559;
    double ang = (double)s * invf[j];
    double k = rint(ang * (1.0 / TWO_PI));
    float fr = (float)(ang - k * TWO_PI);
    float sv, cv;
    __sincosf(fr, &sv, &cv);
    int base = r * H_ + (j >> 2) * 8 + (j & 3);
    csf[base]     = cv;
    csf[base + 4] = sv;
}

// ---------------- B: junction GEMM via bf16 MFMA ----------------
// block = one (b,sign,t), 512 thr = 8 waves, each 64x32 of 128x128 out.
// K=768 as 12 chunks of 64 k (32 pairs). Coefs staged ONCE in LDS (12KB).
// Build is pure f32x4 elementwise (v_pk_fma_f32): granule-blocked xh/cs
// layouts put {x1 x4}{x2 x4} / {c x4}{s x4} in adjacent float4s.
// Single 32KB tile buffer, 2 barriers/chunk. (512,4): no spill (R6/R7 lesson:
// live ~64 VGPR + 32 AGPR unified; caps <128 spill catastrophically).
__global__ __launch_bounds__(512, 4) void junction_mfma(
    const float* __restrict__ xh, const float* __restrict__ csf,
    const float* __restrict__ rpd, const float* __restrict__ rpa,
    const float* __restrict__ rnd, const float* __restrict__ rna,
    const int* __restrict__ org, const int* __restrict__ sp,
    unsigned short* __restrict__ w1) {
    __shared__ __align__(16) unsigned short smem[16384];  // 32KB: tD | tA, 128x64 each
    __shared__ __align__(16) float scof[4 * H_];          // 12KB: scD|ofD|scA|ofA
    __shared__ int vD[P_], vA[P_];
    unsigned short* tD = smem;          // rows of 64 ushorts = 128B
    unsigned short* tA = smem + 8192;

    // bijective XCD swizzle (nwg = 1468, nwg%8 = 4)
    int nwg = gridDim.x;
    int orig = blockIdx.x;
    int xcd = orig & 7;
    int q = nwg >> 3, r8 = nwg & 7;
    int blk = (xcd < r8 ? xcd * (q + 1) : r8 * (q + 1) + (xcd - r8) * q) + (orig >> 3);

    int t = blk % T_;
    int sign = (blk / T_) & 1;
    int b = blk / (2 * T_);
    int o = org[b];
    int gd = sign * 2, ga = sign * 2 + 1;
    const float* pd = sign ? rnd : rpd;
    const float* pa = sign ? rna : rpa;
    int tid = threadIdx.x;

    const float* sc_d = pd + ((size_t)(o * 2 + 0) * T_ + t) * H_;
    const float* of_d = pd + ((size_t)(o * 2 + 1) * T_ + t) * H_;
    const float* sc_a = pa + ((size_t)(o * 2 + 0) * T_ + t) * H_;
    const float* of_a = pa + ((size_t)(o * 2 + 1) * T_ + t) * H_;
    // stage all coefs once (4 x 768 f32)
    for (int e = tid; e < H_; e += 512) {
        scof[e]           = sc_d[e];
        scof[H_ + e]      = of_d[e];
        scof[2 * H_ + e]  = sc_a[e];
        scof[3 * H_ + e]  = of_a[e];
    }
    if (tid < P_) {
        vD[tid] = sp[(b * 4 + gd) * P_ + tid] >= 0;
        vA[tid] = sp[(b * 4 + ga) * P_ + tid] >= 0;
    }
    const float* xd = xh + ((size_t)(b * 4 + gd) * P_) * H_;   // granule-blocked
    const float* xa = xh + ((size_t)(b * 4 + ga) * P_) * H_;
    const float* cd = csf + ((size_t)(b * 4 + gd) * P_) * H_;
    const float* ca = csf + ((size_t)(b * 4 + ga) * P_) * H_;

    int lane = tid & 63, wid = tid >> 6;
    int wrow = (wid >> 2) * 64, wcol = (wid & 3) * 32;
    int lr = lane & 15, lq = lane >> 4;
    int gr0 = (lq ^ (lr & 7)) * 8;     // read granule within 64-ushort row

    f32x4 acc[4][2];
    #pragma unroll
    for (int i = 0; i < 4; ++i)
        #pragma unroll
        for (int j = 0; j < 2; ++j) acc[i][j] = (f32x4){0.f, 0.f, 0.f, 0.f};

    int jp = tid & 7;         // granule: pairs {4jp..4jp+3} of the 32-pair chunk
    int prow = tid >> 3;      // 0..63; p = pass*64 + prow, 2 passes
    int swc = ((jp ^ (prow & 7)) << 3);  // pass-invariant swizzled granule offset

    __syncthreads();          // scof / vD / vA ready

    for (int ch = 0; ch < 12; ++ch) {
        int jb4 = ch * 32 + 4 * jp;    // first pair (j index) of this thread's granule
        // coef reads from LDS (b128, broadcast across prow groups)
        f32x4 s1d = *(const f32x4*)&scof[jb4];
        f32x4 o1d = *(const f32x4*)&scof[H_ + jb4];
        f32x4 s2d = *(const f32x4*)&scof[jb4 + HALF_];
        f32x4 o2d = *(const f32x4*)&scof[H_ + jb4 + HALF_];
        f32x4 s1a = *(const f32x4*)&scof[2 * H_ + jb4];
        f32x4 o1a = *(const f32x4*)&scof[3 * H_ + jb4];
        f32x4 s2a = *(const f32x4*)&scof[2 * H_ + jb4 + HALF_];
        f32x4 o2a = *(const f32x4*)&scof[3 * H_ + jb4 + HALF_];

        if (ch) __syncthreads();   // all MFMA(ch-1) reads done -> safe to overwrite

        #pragma unroll
        for (int pass = 0; pass < 2; ++pass) {
            int p = pass * 64 + prow;
            int sw = p * 64 + swc;
            {   // donor: 4 pairs, pure packed-f32 math
                f32x4 xv1 = *(const f32x4*)(xd + p * H_ + 2 * jb4);      // x1 x4
                f32x4 xv2 = *(const f32x4*)(xd + p * H_ + 2 * jb4 + 4);  // x2 x4
                f32x4 cv  = *(const f32x4*)(cd + p * H_ + 2 * jb4);      // c x4
                f32x4 sv  = *(const f32x4*)(cd + p * H_ + 2 * jb4 + 4);  // s x4
                f32x4 u1 = __builtin_elementwise_fma(s1d, xv1, o1d);
                f32x4 u2 = __builtin_elementwise_fma(s2d, xv2, o2d);
                f32x4 t1 = u2 * sv;
                f32x4 r1 = __builtin_elementwise_fma(u1, cv, -t1);
                f32x4 t2 = u2 * cv;
                f32x4 r2 = __builtin_elementwise_fma(u1, sv, t2);
                uint4 wv;
                wv.x = packbf2(r1.x, r2.x);
                wv.y = packbf2(r1.y, r2.y);
                wv.z = packbf2(r1.z, r2.z);
                wv.w = packbf2(r1.w, r2.w);
                *(uint4*)&tD[sw] = wv;
            }
            {   // acceptor
                f32x4 xv1 = *(const f32x4*)(xa + p * H_ + 2 * jb4);
                f32x4 xv2 = *(const f32x4*)(xa + p * H_ + 2 * jb4 + 4);
                f32x4 cv  = *(const f32x4*)(ca + p * H_ + 2 * jb4);
                f32x4 sv  = *(const f32x4*)(ca + p * H_ + 2 * jb4 + 4);
                f32x4 u1 = __builtin_elementwise_fma(s1a, xv1, o1a);
                f32x4 u2 = __builtin_elementwise_fma(s2a, xv2, o2a);
                f32x4 t1 = u2 * sv;
                f32x4 r1 = __builtin_elementwise_fma(u1, cv, -t1);
                f32x4 t2 = u2 * cv;
                f32x4 r2 = __builtin_elementwise_fma(u1, sv, t2);
                uint4 wv;
                wv.x = packbf2(r1.x, r2.x);
                wv.y = packbf2(r1.y, r2.y);
                wv.z = packbf2(r1.z, r2.z);
                wv.w = packbf2(r1.w, r2.w);
                *(uint4*)&tA[sw] = wv;
            }
        }
        __syncthreads();

        __builtin_amdgcn_s_setprio(1);
        #pragma unroll
        for (int kk = 0; kk < 64; kk += 32) {
            short8 af[4], bf2[2];
            #pragma unroll
            for (int fi = 0; fi < 4; ++fi)
                af[fi] = *(const short8*)&tD[(wrow + fi * 16 + lr) * 64 + (gr0 ^ kk)];
            #pragma unroll
            for (int fj = 0; fj < 2; ++fj)
                bf2[fj] = *(const short8*)&tA[(wcol + fj * 16 + lr) * 64 + (gr0 ^ kk)];
            #pragma unroll
            for (int fi = 0; fi < 4; ++fi)
                #pragma unroll
                for (int fj = 0; fj < 2; ++fj)
                    acc[fi][fj] = __builtin_amdgcn_mfma_f32_16x16x32_bf16(
                        af[fi], bf2[fj], acc[fi][fj], 0, 0, 0);
        }
        __builtin_amdgcn_s_setprio(0);
    }

    // ---- epilogue: softplus+mask -> bf16 LDS stage (32KB) -> coalesced copy ----
    __syncthreads();               // all MFMA reads of smem done before restage
    #pragma unroll
    for (int fi = 0; fi < 4; ++fi) {
        #pragma unroll
        for (int rr = 0; rr < 4; ++rr) {
            int d = wrow + fi * 16 + lq * 4 + rr;
            int vd = vD[d];
            #pragma unroll
            for (int fj = 0; fj < 2; ++fj) {
                int a = wcol + fj * 16 + lr;
                float x = acc[fi][fj][rr];
                float v = 0.0f;
                if (vd && vA[a]) v = (x > 15.0f) ? x : __logf(1.0f + __expf(x));
                smem[d * P_ + a] = packbf1(v);
            }
        }
    }
    __syncthreads();
    const uint4* src4 = (const uint4*)smem;                       // 2048 uint4
    uint4* dst4 = (uint4*)(w1 + ((size_t)((b * 2 + sign) * T_ + t) * P_) * P_);
    for (int i = tid; i < 2048; i += 512) dst4[i] = src4[i];
}

// ---------------- C: transpose bf16 [b][sign][t][d][a] -> f32 [b][d][a][sign*T+t] ----------------
__global__ __launch_bounds__(256) void transpose_out(const __hip_bfloat16* __restrict__ w1,
                                                     float* __restrict__ pred) {
    __shared__ float tile[64 * 129];
    int blk = blockIdx.x;            // bs*128*6 + d*6 + tt   (3072 blocks)
    int tt = blk % 6;
    int d = (blk / 6) % P_;
    int bs = blk / (6 * P_);         // b*2+sign
    int b = bs >> 1, sign = bs & 1;
    int t0 = tt * 64;
    int tcnt = min(64, T_ - t0);
    int tid = threadIdx.x;

    const __hip_bfloat16* src = w1 + (size_t)bs * T_ * P_ * P_ + (size_t)d * P_;
    for (int e = tid; e < tcnt * P_; e += 256) {
        int i = e >> 7, a = e & 127;
        tile[i * 129 + a] = __bfloat162float(src[(size_t)(t0 + i) * P_ * P_ + a]);
    }
    __syncthreads();
    float* dst = pred + ((size_t)(b * P_ + d) * P_) * TT_ + sign * T_ + t0;
    for (int e = tid; e < P_ * 64; e += 256) {
        int a = e >> 6, ii = e & 63;
        if (ii < tcnt) dst[(size_t)a * TT_ + ii] = tile[ii * 129 + a];
    }
}

// ---------------- D: mask fill ----------------
__global__ void mask_fill(const int* __restrict__ sp, float* __restrict__ mask) {
    int blk = blockIdx.x;            // (b*128+d)*128+a   (32768 blocks)
    int a = blk & 127;
    int d = (blk >> 7) & 127;
    int b = blk >> 14;
    bool vp = (sp[(b * 4 + 0) * P_ + d] >= 0) && (sp[(b * 4 + 1) * P_ + a] >= 0);
    bool vn = (sp[(b * 4 + 2) * P_ + d] >= 0) && (sp[(b * 4 + 3) * P_ + a] >= 0);
    float* dst = mask + (size_t)blk * TT_;
    for (int st = threadIdx.x; st < TT_; st += blockDim.x)
        dst[st] = (st < T_ ? vp : vn) ? 1.0f : 0.0f;
}

extern "C" void kernel_launch(void* const* d_in, const int* in_sizes, int n_in,
                              void* d_out, int out_size, void* d_ws, size_t ws_size,
                              hipStream_t stream) {
    const float* emb  = (const float*)d_in[0];
    const float* w    = (const float*)d_in[1];
    const float* bias = (const float*)d_in[2];
    const float* rpd  = (const float*)d_in[3];
    const float* rpa  = (const float*)d_in[4];
    const float* rnd  = (const float*)d_in[5];
    const float* rna  = (const float*)d_in[6];
    const int*   org  = (const int*)d_in[7];
    const int*   sp   = (const int*)d_in[8];

    float* out = (float*)d_out;
    float* ws  = (float*)d_ws;
    float* xh   = ws + XH_OFF;
    float* csf  = ws + CSF_OFF;
    double* invf = (double*)(ws + INVF_OFF);
    unsigned short* xcb = (unsigned short*)(ws + XCB_OFF);
    float* pred  = out;
    float* maskp = out + PRED_ELEMS;
    unsigned short* w1 = (unsigned short*)maskp;   // bf16 staging in mask half

    init_invf<<<1, 384, 0, stream>>>(invf);
    gather_cols<<<1024, 256, 0, stream>>>(emb, sp, xcb);
    rope_table<<<1536, 256, 0, stream>>>(sp, invf, csf);
    dim3 gl(16, 12);
    logits_mfma<<<gl, 256, 0, stream>>>(xcb, w, bias, org, xh);
    junction_mfma<<<2 * 2 * T_, 512, 0, stream>>>(xh, csf, rpd, rpa, rnd, rna, org, sp, w1);
    transpose_out<<<2 * 2 * P_ * 6, 256, 0, stream>>>((const __hip_bfloat16*)w1, pred);
    mask_fill<<<32768, 256, 0, stream>>>(sp, maskp);
}

// Round 11
// 217.369 us; speedup vs baseline: 3.8228x; 1.2418x over previous
//
#include <hip/hip_runtime.h>
#include <hip/hip_bf16.h>
#include <math.h>
#include <string.h>

#define B_    2
#define C_    1536
#define S_    16384
#define H_    768
#define T_    367
#define P_    128
#define HALF_ 384
#define TT_   734                 // 2*T
#define PRED_ELEMS 24051712      // B*P*P*2T

// ws layout (float slots)
// xhh: [r][granule g][ {x1 x4 f16}{x2 x4 f16} ]  ushort idx = r*768 + g*8 + sel*4 + (hj&3)
// csh: [r][granule g][ {c x4 f16}{s x4 f16} ]
#define XHH_OFF  0               // 786,432 ushorts = 393,216 f32 slots
#define CSH_OFF  393216          // 786,432 ushorts
#define INVF_OFF 786432          // 384 doubles (768 slots)
#define XCB_OFF  787200          // [B*4*P][C] bf16 = 1,572,864 ushorts

typedef short short8 __attribute__((ext_vector_type(8)));
typedef _Float16 f16x8 __attribute__((ext_vector_type(8)));
typedef _Float16 h2    __attribute__((ext_vector_type(2)));
typedef float f32x4  __attribute__((ext_vector_type(4)));

__device__ __forceinline__ unsigned int packbf2(float a, float b) {
    __hip_bfloat162 h = __float22bfloat162_rn(make_float2(a, b));
    unsigned int r; __builtin_memcpy(&r, &h, 4); return r;
}
__device__ __forceinline__ unsigned short packbf1(float a) {
    __hip_bfloat16 h = __float2bfloat16(a);
    unsigned short r; __builtin_memcpy(&r, &h, 2); return r;
}
__device__ __forceinline__ unsigned short f2h(float x) {
    _Float16 h = (_Float16)x;
    unsigned short r; __builtin_memcpy(&r, &h, 2); return r;
}
__device__ __forceinline__ h2 bch(unsigned int v) { h2 r; __builtin_memcpy(&r, &v, 4); return r; }
__device__ __forceinline__ unsigned int hcb(h2 v) { unsigned int r; __builtin_memcpy(&r, &v, 4); return r; }

// ---------------- A0: gather embedding columns -> bf16 ----------------
__global__ void gather_cols(const float* __restrict__ emb,
                            const int* __restrict__ sp,
                            unsigned short* __restrict__ xcb) {
    int blk = blockIdx.x;           // B*4*P = 1024
    int p = blk & 127;
    int g = (blk >> 7) & 3;
    int b = blk >> 9;
    int s = sp[(b * 4 + g) * P_ + p];
    const float* src = emb + (size_t)b * C_ * S_ + s;
    unsigned short* dst = xcb + ((size_t)(b * 4 + g) * P_ + p) * C_;
    for (int c = threadIdx.x; c < C_; c += blockDim.x)
        dst[c] = packbf1(src[(size_t)c * S_]);
}

// ---------------- A1: gathered-logits GEMM via bf16 MFMA, 64x64 tiles ----------------
// writes xhh as packed-f16 granules: idx = r*768 + (hj>>2)*8 + sel*4 + (hj&3)
__global__ __launch_bounds__(256) void logits_mfma(
    const unsigned short* __restrict__ xcb, const float* __restrict__ w,
    const float* __restrict__ bias, const int* __restrict__ org,
    unsigned short* __restrict__ xhh) {
    __shared__ __align__(16) unsigned short tX[64 * 64];   // 8KB
    __shared__ __align__(16) unsigned short tW[64 * 64];   // 8KB
    int mt = blockIdx.x;             // 0..15 (rows of 64)
    int nt = blockIdx.y;             // 0..11 (cols of 64)
    int o = org[mt >> 3];
    int r0 = mt * 64, h0 = nt * 64;
    int tid = threadIdx.x;
    int lane = tid & 63, wid = tid >> 6;
    int wrow = (wid >> 1) * 32, wcol = (wid & 1) * 32;
    int lr = lane & 15, lq = lane >> 4;
    int gr0 = (lq ^ (lr & 7)) * 8;

    f32x4 acc[2][2];
    #pragma unroll
    for (int i = 0; i < 2; ++i)
        #pragma unroll
        for (int j = 0; j < 2; ++j) acc[i][j] = (f32x4){0.f, 0.f, 0.f, 0.f};

    int srow = tid >> 2, sg = tid & 3;   // staging: 4 thr/row, 2 granules each

    for (int kc = 0; kc < C_; kc += 64) {
        if (kc) __syncthreads();
        {   // stage X (bf16 direct)
            const unsigned short* src = xcb + (size_t)(r0 + srow) * C_ + kc;
            unsigned short* drow = tX + srow * 64;
            #pragma unroll
            for (int i = 0; i < 2; ++i) {
                int g = sg + i * 4;
                uint4 v = *(const uint4*)(src + g * 8);
                *(uint4*)&drow[(g ^ (srow & 7)) * 8] = v;
            }
        }
        {   // stage W (f32 -> bf16)
            const float* srcw = w + ((size_t)o * H_ + h0 + srow) * C_ + kc;
            unsigned short* drow = tW + srow * 64;
            #pragma unroll
            for (int i = 0; i < 2; ++i) {
                int g = sg + i * 4;
                float4 v0 = *(const float4*)(srcw + g * 8);
                float4 v1 = *(const float4*)(srcw + g * 8 + 4);
                uint4 pk;
                pk.x = packbf2(v0.x, v0.y); pk.y = packbf2(v0.z, v0.w);
                pk.z = packbf2(v1.x, v1.y); pk.w = packbf2(v1.z, v1.w);
                *(uint4*)&drow[(g ^ (srow & 7)) * 8] = pk;
            }
        }
        __syncthreads();
        #pragma unroll
        for (int kk = 0; kk < 64; kk += 32) {
            short8 af[2], bf2[2];
            #pragma unroll
            for (int fi = 0; fi < 2; ++fi)
                af[fi] = *(const short8*)&tX[(wrow + fi * 16 + lr) * 64 + (gr0 ^ kk)];
            #pragma unroll
            for (int fj = 0; fj < 2; ++fj)
                bf2[fj] = *(const short8*)&tW[(wcol + fj * 16 + lr) * 64 + (gr0 ^ kk)];
            #pragma unroll
            for (int fi = 0; fi < 2; ++fi)
                #pragma unroll
                for (int fj = 0; fj < 2; ++fj)
                    acc[fi][fj] = __builtin_amdgcn_mfma_f32_16x16x32_bf16(
                        af[fi], bf2[fj], acc[fi][fj], 0, 0, 0);
        }
    }
    #pragma unroll
    for (int fi = 0; fi < 2; ++fi)
        #pragma unroll
        for (int rr = 0; rr < 4; ++rr) {
            int r = r0 + wrow + fi * 16 + lq * 4 + rr;
            #pragma unroll
            for (int fj = 0; fj < 2; ++fj) {
                int h = h0 + wcol + fj * 16 + lr;
                int hj = (h < HALF_) ? h : (h - HALF_);
                int sel = (h < HALF_) ? 0 : 1;
                xhh[(size_t)r * H_ + (hj >> 2) * 8 + sel * 4 + (hj & 3)] =
                    f2h(acc[fi][fj][rr] + bias[o * H_ + h]);
            }
        }
}

// ---------------- A2a: inv-freq table (fp64) ----------------
__global__ void init_invf(double* __restrict__ invf) {
    int j = threadIdx.x;
    if (j < HALF_) invf[j] = exp2(-20.0 * (double)j / 384.0);
}

// ---------------- A2b: RoPE cos/sin table, packed-f16 granules {c x4}{s x4} ----------------
__global__ void rope_table(const int* __restrict__ sp,
                           const double* __restrict__ invf,
                           unsigned short* __restrict__ csh) {
    int e = blockIdx.x * blockDim.x + threadIdx.x;  // 1024*384
    if (e >= B_ * 4 * P_ * HALF_) return;
    int j = e % HALF_;
    int r = e / HALF_;
    int s = sp[r];
    const double TWO_PI = 6.283185307179586476925286766559;
    double ang = (double)s * invf[j];
    double k = rint(ang * (1.0 / TWO_PI));
    float fr = (float)(ang - k * TWO_PI);
    float sv, cv;
    __sincosf(fr, &sv, &cv);
    int base = r * H_ + (j >> 2) * 8 + (j & 3);
    csh[base]     = f2h(cv);
    csh[base + 4] = f2h(sv);
}

// ---------------- B: junction GEMM via f16 MFMA ----------------
// block = one (b,sign,t), 512 thr = 8 waves, each 64x32 of 128x128 out.
// K=768 as 12 chunks of 64 k (32 pairs = 8 granules). All tile-path data f16:
// x/cs loads are 16B packed granules (halved L2 stream vs f32), build is pure
// v_pk_fma_f16 (12 ops/granule, no unpack/cvt; k-order = {r1 x4, r2 x4} per
// granule — valid since dot products are k-order-invariant, both sides match).
// Double-buffered tiles (2x32KB), ONE barrier/chunk (R5-proven: wave at
// build(ch) has crossed bar(ch-1), which every wave reaches only after its
// build(ch-1), which follows its mfma(ch-2) — so buf[ch&1] is free).
// (512,4): no-spill floor lesson from R6/R7 (live VGPR + 32 AGPR unified).
__global__ __launch_bounds__(512, 4) void junction_mfma(
    const unsigned short* __restrict__ xhh, const unsigned short* __restrict__ csh,
    const float* __restrict__ rpd, const float* __restrict__ rpa,
    const float* __restrict__ rnd, const float* __restrict__ rna,
    const int* __restrict__ org, const int* __restrict__ sp,
    unsigned short* __restrict__ w1) {
    __shared__ __align__(16) unsigned short smem[32768];  // 64KB: [2 buf][tD|tA][128*64]
    __shared__ __align__(16) unsigned short scofh[4 * H_]; // 6KB f16: scD|ofD|scA|ofA (granule layout)
    __shared__ int vD[P_], vA[P_];

    // bijective XCD swizzle (nwg = 1468, nwg%8 = 4)
    int nwg = gridDim.x;
    int orig = blockIdx.x;
    int xcd = orig & 7;
    int q = nwg >> 3, r8 = nwg & 7;
    int blk = (xcd < r8 ? xcd * (q + 1) : r8 * (q + 1) + (xcd - r8) * q) + (orig >> 3);

    int t = blk % T_;
    int sign = (blk / T_) & 1;
    int b = blk / (2 * T_);
    int o = org[b];
    int gd = sign * 2, ga = sign * 2 + 1;
    const float* pd = sign ? rnd : rpd;
    const float* pa = sign ? rna : rpa;
    int tid = threadIdx.x;

    const float* sc_d = pd + ((size_t)(o * 2 + 0) * T_ + t) * H_;
    const float* of_d = pd + ((size_t)(o * 2 + 1) * T_ + t) * H_;
    const float* sc_a = pa + ((size_t)(o * 2 + 0) * T_ + t) * H_;
    const float* of_a = pa + ((size_t)(o * 2 + 1) * T_ + t) * H_;
    // stage coefs once, f16, granule layout {s1 x4}{s2 x4}
    for (int e = tid; e < H_; e += 512) {
        int hj = (e < HALF_) ? e : (e - HALF_);
        int pos = (hj >> 2) * 8 + ((e < HALF_) ? 0 : 4) + (hj & 3);
        scofh[pos]           = f2h(sc_d[e]);
        scofh[H_ + pos]      = f2h(of_d[e]);
        scofh[2 * H_ + pos]  = f2h(sc_a[e]);
        scofh[3 * H_ + pos]  = f2h(of_a[e]);
    }
    if (tid < P_) {
        vD[tid] = sp[(b * 4 + gd) * P_ + tid] >= 0;
        vA[tid] = sp[(b * 4 + ga) * P_ + tid] >= 0;
    }
    const unsigned short* xdh = xhh + ((size_t)(b * 4 + gd) * P_) * H_;
    const unsigned short* xah = xhh + ((size_t)(b * 4 + ga) * P_) * H_;
    const unsigned short* cdh = csh + ((size_t)(b * 4 + gd) * P_) * H_;
    const unsigned short* cah = csh + ((size_t)(b * 4 + ga) * P_) * H_;

    int lane = tid & 63, wid = tid >> 6;
    int wrow = (wid >> 2) * 64, wcol = (wid & 3) * 32;
    int lr = lane & 15, lq = lane >> 4;
    int gr0 = (lq ^ (lr & 7)) * 8;     // read granule within 64-ushort row

    f32x4 acc[4][2];
    #pragma unroll
    for (int i = 0; i < 4; ++i)
        #pragma unroll
        for (int j = 0; j < 2; ++j) acc[i][j] = (f32x4){0.f, 0.f, 0.f, 0.f};

    int jp = tid & 7;         // granule: pairs {4jp..4jp+3} of the 32-pair chunk
    int prow = tid >> 3;      // 0..63; p = pass*64 + prow, 2 passes
    int swc = ((jp ^ (prow & 7)) << 3);  // pass-invariant swizzled granule offset

    __syncthreads();          // scofh / vD / vA ready

    for (int ch = 0; ch < 12; ++ch) {
        int kb = (ch * 8 + jp) * 8;    // ushort offset of this thread's granule
        unsigned short* tDc = smem + (ch & 1) * 16384;
        unsigned short* tAc = tDc + 8192;

        // coef granules (LDS b128, broadcast across prow)
        uint4 scd = *(const uint4*)&scofh[kb];
        uint4 ofd = *(const uint4*)&scofh[H_ + kb];
        uint4 sca = *(const uint4*)&scofh[2 * H_ + kb];
        uint4 ofa = *(const uint4*)&scofh[3 * H_ + kb];

        #pragma unroll
        for (int pass = 0; pass < 2; ++pass) {
            int p = pass * 64 + prow;
            int sw = p * 64 + swc;
            {   // donor: one 16B x-granule + one 16B cs-granule, 12 pk_f16 ops
                uint4 xv = *(const uint4*)(xdh + p * H_ + kb);   // x1_01,x1_23,x2_01,x2_23
                uint4 cv = *(const uint4*)(cdh + p * H_ + kb);   // c_01,c_23,s_01,s_23
                h2 u1a = __builtin_elementwise_fma(bch(scd.x), bch(xv.x), bch(ofd.x));
                h2 u1b = __builtin_elementwise_fma(bch(scd.y), bch(xv.y), bch(ofd.y));
                h2 u2a = __builtin_elementwise_fma(bch(scd.z), bch(xv.z), bch(ofd.z));
                h2 u2b = __builtin_elementwise_fma(bch(scd.w), bch(xv.w), bch(ofd.w));
                h2 cA = bch(cv.x), cB = bch(cv.y), sA = bch(cv.z), sB = bch(cv.w);
                h2 r1a = __builtin_elementwise_fma(u1a, cA, -(u2a * sA));
                h2 r1b = __builtin_elementwise_fma(u1b, cB, -(u2b * sB));
                h2 r2a = __builtin_elementwise_fma(u1a, sA, u2a * cA);
                h2 r2b = __builtin_elementwise_fma(u1b, sB, u2b * cB);
                uint4 wv;
                wv.x = hcb(r1a); wv.y = hcb(r1b); wv.z = hcb(r2a); wv.w = hcb(r2b);
                *(uint4*)&tDc[sw] = wv;
            }
            {   // acceptor
                uint4 xv = *(const uint4*)(xah + p * H_ + kb);
                uint4 cv = *(const uint4*)(cah + p * H_ + kb);
                h2 u1a = __builtin_elementwise_fma(bch(sca.x), bch(xv.x), bch(ofa.x));
                h2 u1b = __builtin_elementwise_fma(bch(sca.y), bch(xv.y), bch(ofa.y));
                h2 u2a = __builtin_elementwise_fma(bch(sca.z), bch(xv.z), bch(ofa.z));
                h2 u2b = __builtin_elementwise_fma(bch(sca.w), bch(xv.w), bch(ofa.w));
                h2 cA = bch(cv.x), cB = bch(cv.y), sA = bch(cv.z), sB = bch(cv.w);
                h2 r1a = __builtin_elementwise_fma(u1a, cA, -(u2a * sA));
                h2 r1b = __builtin_elementwise_fma(u1b, cB, -(u2b * sB));
                h2 r2a = __builtin_elementwise_fma(u1a, sA, u2a * cA);
                h2 r2b = __builtin_elementwise_fma(u1b, sB, u2b * cB);
                uint4 wv;
                wv.x = hcb(r1a); wv.y = hcb(r1b); wv.z = hcb(r2a); wv.w = hcb(r2b);
                *(uint4*)&tAc[sw] = wv;
            }
        }
        __syncthreads();   // buf built; also guarantees buf was free (see header)

        __builtin_amdgcn_s_setprio(1);
        #pragma unroll
        for (int kk = 0; kk < 64; kk += 32) {
            f16x8 af[4], bf2[2];
            #pragma unroll
            for (int fi = 0; fi < 4; ++fi)
                af[fi] = *(const f16x8*)&tDc[(wrow + fi * 16 + lr) * 64 + (gr0 ^ kk)];
            #pragma unroll
            for (int fj = 0; fj < 2; ++fj)
                bf2[fj] = *(const f16x8*)&tAc[(wcol + fj * 16 + lr) * 64 + (gr0 ^ kk)];
            #pragma unroll
            for (int fi = 0; fi < 4; ++fi)
                #pragma unroll
                for (int fj = 0; fj < 2; ++fj)
                    acc[fi][fj] = __builtin_amdgcn_mfma_f32_16x16x32_f16(
                        af[fi], bf2[fj], acc[fi][fj], 0, 0, 0);
        }
        __builtin_amdgcn_s_setprio(0);
    }

    // ---- epilogue: softplus+mask -> bf16 LDS stage (buf0, 32KB) -> coalesced copy ----
    // last chunk (ch=11) read buf1; all waves are past build(11) => past mfma(10),
    // so buf0 is dead. Stage there while stragglers finish mfma(11) in buf1.
    #pragma unroll
    for (int fi = 0; fi < 4; ++fi) {
        #pragma unroll
        for (int rr = 0; rr < 4; ++rr) {
            int d = wrow + fi * 16 + lq * 4 + rr;
            int vd = vD[d];
            #pragma unroll
            for (int fj = 0; fj < 2; ++fj) {
                int a = wcol + fj * 16 + lr;
                float x = acc[fi][fj][rr];
                float v = 0.0f;
                if (vd && vA[a]) v = (x > 15.0f) ? x : __logf(1.0f + __expf(x));
                smem[d * P_ + a] = packbf1(v);
            }
        }
    }
    __syncthreads();
    const uint4* src4 = (const uint4*)smem;                       // 2048 uint4
    uint4* dst4 = (uint4*)(w1 + ((size_t)((b * 2 + sign) * T_ + t) * P_) * P_);
    for (int i = tid; i < 2048; i += 512) dst4[i] = src4[i];
}

// ---------------- C: transpose bf16 [b][sign][t][d][a] -> f32 [b][d][a][sign*T+t] ----------------
__global__ __launch_bounds__(256) void transpose_out(const __hip_bfloat16* __restrict__ w1,
                                                     float* __restrict__ pred) {
    __shared__ float tile[64 * 129];
    int blk = blockIdx.x;            // bs*128*6 + d*6 + tt   (3072 blocks)
    int tt = blk % 6;
    int d = (blk / 6) % P_;
    int bs = blk / (6 * P_);         // b*2+sign
    int b = bs >> 1, sign = bs & 1;
    int t0 = tt * 64;
    int tcnt = min(64, T_ - t0);
    int tid = threadIdx.x;

    const __hip_bfloat16* src = w1 + (size_t)bs * T_ * P_ * P_ + (size_t)d * P_;
    for (int e = tid; e < tcnt * P_; e += 256) {
        int i = e >> 7, a = e & 127;
        tile[i * 129 + a] = __bfloat162float(src[(size_t)(t0 + i) * P_ * P_ + a]);
    }
    __syncthreads();
    float* dst = pred + ((size_t)(b * P_ + d) * P_) * TT_ + sign * T_ + t0;
    for (int e = tid; e < P_ * 64; e += 256) {
        int a = e >> 6, ii = e & 63;
        if (ii < tcnt) dst[(size_t)a * TT_ + ii] = tile[ii * 129 + a];
    }
}

// ---------------- D: mask fill ----------------
__global__ void mask_fill(const int* __restrict__ sp, float* __restrict__ mask) {
    int blk = blockIdx.x;            // (b*128+d)*128+a   (32768 blocks)
    int a = blk & 127;
    int d = (blk >> 7) & 127;
    int b = blk >> 14;
    bool vp = (sp[(b * 4 + 0) * P_ + d] >= 0) && (sp[(b * 4 + 1) * P_ + a] >= 0);
    bool vn = (sp[(b * 4 + 2) * P_ + d] >= 0) && (sp[(b * 4 + 3) * P_ + a] >= 0);
    float* dst = mask + (size_t)blk * TT_;
    for (int st = threadIdx.x; st < TT_; st += blockDim.x)
        dst[st] = (st < T_ ? vp : vn) ? 1.0f : 0.0f;
}

extern "C" void kernel_launch(void* const* d_in, const int* in_sizes, int n_in,
                              void* d_out, int out_size, void* d_ws, size_t ws_size,
                              hipStream_t stream) {
    const float* emb  = (const float*)d_in[0];
    const float* w    = (const float*)d_in[1];
    const float* bias = (const float*)d_in[2];
    const float* rpd  = (const float*)d_in[3];
    const float* rpa  = (const float*)d_in[4];
    const float* rnd  = (const float*)d_in[5];
    const float* rna  = (const float*)d_in[6];
    const int*   org  = (const int*)d_in[7];
    const int*   sp   = (const int*)d_in[8];

    float* out = (float*)d_out;
    float* ws  = (float*)d_ws;
    unsigned short* xhh = (unsigned short*)(ws + XHH_OFF);
    unsigned short* csh = (unsigned short*)(ws + CSH_OFF);
    double* invf = (double*)(ws + INVF_OFF);
    unsigned short* xcb = (unsigned short*)(ws + XCB_OFF);
    float* pred  = out;
    float* maskp = out + PRED_ELEMS;
    unsigned short* w1 = (unsigned short*)maskp;   // bf16 staging in mask half

    init_invf<<<1, 384, 0, stream>>>(invf);
    gather_cols<<<1024, 256, 0, stream>>>(emb, sp, xcb);
    rope_table<<<1536, 256, 0, stream>>>(sp, invf, csh);
    dim3 gl(16, 12);
    logits_mfma<<<gl, 256, 0, stream>>>(xcb, w, bias, org, xhh);
    junction_mfma<<<2 * 2 * T_, 512, 0, stream>>>(xhh, csh, rpd, rpa, rnd, rna, org, sp, w1);
    transpose_out<<<2 * 2 * P_ * 6, 256, 0, stream>>>((const __hip_bfloat16*)w1, pred);
    mask_fill<<<32768, 256, 0, stream>>>(sp, maskp);
}

// Round 13
// 214.502 us; speedup vs baseline: 3.8739x; 1.0134x over previous
//
#include <hip/hip_runtime.h>
#include <hip/hip_bf16.h>
#include <math.h>
#include <string.h>

#define B_    2
#define C_    1536
#define S_    16384
#define H_    768
#define T_    367
#define P_    128
#define HALF_ 384
#define TT_   734                 // 2*T
#define NT2_  184                 // ceil(T/2) t-pairs
#define PRED_ELEMS 24051712      // B*P*P*2T

// ws layout (float slots)
// xhh: [r][granule g][ {x1 x4 f16}{x2 x4 f16} ]  ushort idx = r*768 + g*8 + sel*4 + (hj&3)
// csh: [r][granule g][ {c x4 f16}{s x4 f16} ]
#define XHH_OFF  0               // 786,432 ushorts = 393,216 f32 slots
#define CSH_OFF  393216          // 786,432 ushorts
#define INVF_OFF 786432          // 384 doubles (768 slots)
#define XCB_OFF  787200          // [B*4*P][C] bf16 = 1,572,864 ushorts

typedef short short8 __attribute__((ext_vector_type(8)));
typedef _Float16 f16x8 __attribute__((ext_vector_type(8)));
typedef _Float16 h2    __attribute__((ext_vector_type(2)));
typedef float f32x4  __attribute__((ext_vector_type(4)));

__device__ __forceinline__ unsigned int packbf2(float a, float b) {
    __hip_bfloat162 h = __float22bfloat162_rn(make_float2(a, b));
    unsigned int r; __builtin_memcpy(&r, &h, 4); return r;
}
__device__ __forceinline__ unsigned short packbf1(float a) {
    __hip_bfloat16 h = __float2bfloat16(a);
    unsigned short r; __builtin_memcpy(&r, &h, 2); return r;
}
__device__ __forceinline__ unsigned short f2h(float x) {
    _Float16 h = (_Float16)x;
    unsigned short r; __builtin_memcpy(&r, &h, 2); return r;
}
__device__ __forceinline__ h2 bch(unsigned int v) { h2 r; __builtin_memcpy(&r, &v, 4); return r; }
__device__ __forceinline__ unsigned int hcb(h2 v) { unsigned int r; __builtin_memcpy(&r, &v, 4); return r; }

// ---------------- A0: gather embedding columns -> bf16 ----------------
__global__ void gather_cols(const float* __restrict__ emb,
                            const int* __restrict__ sp,
                            unsigned short* __restrict__ xcb) {
    int blk = blockIdx.x;           // B*4*P = 1024
    int p = blk & 127;
    int g = (blk >> 7) & 3;
    int b = blk >> 9;
    int s = sp[(b * 4 + g) * P_ + p];
    const float* src = emb + (size_t)b * C_ * S_ + s;
    unsigned short* dst = xcb + ((size_t)(b * 4 + g) * P_ + p) * C_;
    for (int c = threadIdx.x; c < C_; c += blockDim.x)
        dst[c] = packbf1(src[(size_t)c * S_]);
}

// ---------------- A1: gathered-logits GEMM via bf16 MFMA, 64x64 tiles ----------------
// writes xhh as packed-f16 granules: idx = r*768 + (hj>>2)*8 + sel*4 + (hj&3)
__global__ __launch_bounds__(256) void logits_mfma(
    const unsigned short* __restrict__ xcb, const float* __restrict__ w,
    const float* __restrict__ bias, const int* __restrict__ org,
    unsigned short* __restrict__ xhh) {
    __shared__ __align__(16) unsigned short tX[64 * 64];   // 8KB
    __shared__ __align__(16) unsigned short tW[64 * 64];   // 8KB
    int mt = blockIdx.x;             // 0..15 (rows of 64)
    int nt = blockIdx.y;             // 0..11 (cols of 64)
    int o = org[mt >> 3];
    int r0 = mt * 64, h0 = nt * 64;
    int tid = threadIdx.x;
    int lane = tid & 63, wid = tid >> 6;
    int wrow = (wid >> 1) * 32, wcol = (wid & 1) * 32;
    int lr = lane & 15, lq = lane >> 4;
    int gr0 = (lq ^ (lr & 7)) * 8;

    f32x4 acc[2][2];
    #pragma unroll
    for (int i = 0; i < 2; ++i)
        #pragma unroll
        for (int j = 0; j < 2; ++j) acc[i][j] = (f32x4){0.f, 0.f, 0.f, 0.f};

    int srow = tid >> 2, sg = tid & 3;   // staging: 4 thr/row, 2 granules each

    for (int kc = 0; kc < C_; kc += 64) {
        if (kc) __syncthreads();
        {   // stage X (bf16 direct)
            const unsigned short* src = xcb + (size_t)(r0 + srow) * C_ + kc;
            unsigned short* drow = tX + srow * 64;
            #pragma unroll
            for (int i = 0; i < 2; ++i) {
                int g = sg + i * 4;
                uint4 v = *(const uint4*)(src + g * 8);
                *(uint4*)&drow[(g ^ (srow & 7)) * 8] = v;
            }
        }
        {   // stage W (f32 -> bf16)
            const float* srcw = w + ((size_t)o * H_ + h0 + srow) * C_ + kc;
            unsigned short* drow = tW + srow * 64;
            #pragma unroll
            for (int i = 0; i < 2; ++i) {
                int g = sg + i * 4;
                float4 v0 = *(const float4*)(srcw + g * 8);
                float4 v1 = *(const float4*)(srcw + g * 8 + 4);
                uint4 pk;
                pk.x = packbf2(v0.x, v0.y); pk.y = packbf2(v0.z, v0.w);
                pk.z = packbf2(v1.x, v1.y); pk.w = packbf2(v1.z, v1.w);
                *(uint4*)&drow[(g ^ (srow & 7)) * 8] = pk;
            }
        }
        __syncthreads();
        #pragma unroll
        for (int kk = 0; kk < 64; kk += 32) {
            short8 af[2], bf2[2];
            #pragma unroll
            for (int fi = 0; fi < 2; ++fi)
                af[fi] = *(const short8*)&tX[(wrow + fi * 16 + lr) * 64 + (gr0 ^ kk)];
            #pragma unroll
            for (int fj = 0; fj < 2; ++fj)
                bf2[fj] = *(const short8*)&tW[(wcol + fj * 16 + lr) * 64 + (gr0 ^ kk)];
            #pragma unroll
            for (int fi = 0; fi < 2; ++fi)
                #pragma unroll
                for (int fj = 0; fj < 2; ++fj)
                    acc[fi][fj] = __builtin_amdgcn_mfma_f32_16x16x32_bf16(
                        af[fi], bf2[fj], acc[fi][fj], 0, 0, 0);
        }
    }
    #pragma unroll
    for (int fi = 0; fi < 2; ++fi)
        #pragma unroll
        for (int rr = 0; rr < 4; ++rr) {
            int r = r0 + wrow + fi * 16 + lq * 4 + rr;
            #pragma unroll
            for (int fj = 0; fj < 2; ++fj) {
                int h = h0 + wcol + fj * 16 + lr;
                int hj = (h < HALF_) ? h : (h - HALF_);
                int sel = (h < HALF_) ? 0 : 1;
                xhh[(size_t)r * H_ + (hj >> 2) * 8 + sel * 4 + (hj & 3)] =
                    f2h(acc[fi][fj][rr] + bias[o * H_ + h]);
            }
        }
}

// ---------------- A2a: inv-freq table (fp64) ----------------
__global__ void init_invf(double* __restrict__ invf) {
    int j = threadIdx.x;
    if (j < HALF_) invf[j] = exp2(-20.0 * (double)j / 384.0);
}

// ---------------- A2b: RoPE cos/sin table, packed-f16 granules {c x4}{s x4} ----------------
__global__ void rope_table(const int* __restrict__ sp,
                           const double* __restrict__ invf,
                           unsigned short* __restrict__ csh) {
    int e = blockIdx.x * blockDim.x + threadIdx.x;  // 1024*384
    if (e >= B_ * 4 * P_ * HALF_) return;
    int j = e % HALF_;
    int r = e / HALF_;
    int s = sp[r];
    const double TWO_PI = 6.283185307179586476925286766559;
    double ang = (double)s * invf[j];
    double k = rint(ang * (1.0 / TWO_PI));
    float fr = (float)(ang - k * TWO_PI);
    float sv, cv;
    __sincosf(fr, &sv, &cv);
    int base = r * H_ + (j >> 2) * 8 + (j & 3);
    csh[base]     = f2h(cv);
    csh[base + 4] = f2h(sv);
}

// ---------------- B: junction GEMM via f16 MFMA, 2 t per block ----------------
// block = one (b, sign, t-pair): 1024 thr = 16 waves, each a 32x32 tile per t.
// x/cs granule loads are t-invariant -> loaded ONCE for both t tiles (VMEM
// instrs and L2 stream halved vs 1-t blocks). K=768 as 12 chunks of 64 k.
// Double-buffered tiles [buf2][t2][side2][128x64] = 128KB + 12KB f16 coefs;
// 1 barrier/chunk (induction: a wave at build(ch) passed bar(ch-1), so all
// waves finished build(ch-1) > their mfma(ch-2) -> buf(ch&1) free).
// (1024,4): VGPR cap 128, acc = 2t x 16 = 32 regs, live ~100 -> no spill.
// NOTE: w1 lives in the MASK HALF of d_out; mask_fill must stay a SEPARATE
// kernel launched after transpose_out (R12 lesson: fusing mask writes with
// w1 reads races across blocks).
__global__ __launch_bounds__(1024, 4) void junction_mfma(
    const unsigned short* __restrict__ xhh, const unsigned short* __restrict__ csh,
    const float* __restrict__ rpd, const float* __restrict__ rpa,
    const float* __restrict__ rnd, const float* __restrict__ rna,
    const int* __restrict__ org, const int* __restrict__ sp,
    unsigned short* __restrict__ w1) {
    __shared__ __align__(16) unsigned short smem[65536];   // 128KB tiles
    __shared__ __align__(16) unsigned short scofh[6144];   // 12KB: [t][side][sc|of][768]
    __shared__ int vD[P_], vA[P_];

    // bijective XCD swizzle (nwg = 736, %8 == 0)
    int nwg = gridDim.x;
    int orig = blockIdx.x;
    int xcd = orig & 7;
    int q = nwg >> 3, r8 = nwg & 7;
    int blk = (xcd < r8 ? xcd * (q + 1) : r8 * (q + 1) + (xcd - r8) * q) + (orig >> 3);

    int tp = blk % NT2_;
    int sign = (blk / NT2_) & 1;
    int b = blk / (2 * NT2_);
    int o = org[b];
    int t0 = 2 * tp, t1 = t0 + 1;
    int t1ok = (t1 < T_);
    int t1c = t1ok ? t1 : t0;       // clamped for coef reads
    int gd = sign * 2, ga = sign * 2 + 1;
    const float* pd = sign ? rnd : rpd;
    const float* pa = sign ? rna : rpa;
    int tid = threadIdx.x;

    // stage coefs for both t, f16, granule layout {s1 x4}{s2 x4}
    for (int e = tid; e < 6144; e += 1024) {
        int tsel = e / 3072;
        int rem = e - tsel * 3072;
        int side = rem / 1536;
        int rem2 = rem - side * 1536;
        int arr = rem2 / 768;              // 0 = scale, 1 = offset
        int e2 = rem2 - arr * 768;
        int tt = tsel ? t1c : t0;
        const float* base = (side ? pa : pd) + ((size_t)(o * 2 + arr) * T_ + tt) * H_;
        int hj = (e2 < HALF_) ? e2 : (e2 - HALF_);
        int sel = (e2 < HALF_) ? 0 : 1;
        int pos = (hj >> 2) * 8 + sel * 4 + (hj & 3);
        scofh[((tsel * 2 + side) * 2 + arr) * 768 + pos] = f2h(base[e2]);
    }
    if (tid < P_) {
        vD[tid] = sp[(b * 4 + gd) * P_ + tid] >= 0;
        vA[tid] = sp[(b * 4 + ga) * P_ + tid] >= 0;
    }
    const unsigned short* xdh = xhh + ((size_t)(b * 4 + gd) * P_) * H_;
    const unsigned short* xah = xhh + ((size_t)(b * 4 + ga) * P_) * H_;
    const unsigned short* cdh = csh + ((size_t)(b * 4 + gd) * P_) * H_;
    const unsigned short* cah = csh + ((size_t)(b * 4 + ga) * P_) * H_;

    int lane = tid & 63, wid = tid >> 6;            // wid 0..15
    int wrow = (wid >> 2) * 32, wcol = (wid & 3) * 32;
    int lr = lane & 15, lq = lane >> 4;
    int gr0 = (lq ^ (lr & 7)) * 8;

    f32x4 a0[2][2], a1[2][2];
    #pragma unroll
    for (int i = 0; i < 2; ++i)
        #pragma unroll
        for (int j = 0; j < 2; ++j) {
            a0[i][j] = (f32x4){0.f, 0.f, 0.f, 0.f};
            a1[i][j] = (f32x4){0.f, 0.f, 0.f, 0.f};
        }

    __syncthreads();          // scofh / vD / vA ready

    for (int ch = 0; ch < 12; ++ch) {
        unsigned short* bufb = smem + (ch & 1) * 32768;

        #pragma unroll
        for (int s = 0; s < 2; ++s) {
            int slot = tid + s * 1024;          // 2048 (row, gran) slots
            int row = slot >> 3, gran = slot & 7;
            int side = row >> 7, prow = row & 127;
            const unsigned short* xb = side ? xah : xdh;
            const unsigned short* cb = side ? cah : cdh;
            int off = prow * H_ + ch * 64 + gran * 8;
            uint4 xv = *(const uint4*)(xb + off);   // x1_01,x1_23,x2_01,x2_23
            uint4 cv = *(const uint4*)(cb + off);   // c_01,c_23,s_01,s_23
            int sw = prow * 64 + ((gran ^ (prow & 7)) << 3);
            int kb = (ch * 8 + gran) * 8;
            h2 cA = bch(cv.x), cB = bch(cv.y), sA = bch(cv.z), sB = bch(cv.w);
            {   // t0 build
                const unsigned short* cof = scofh + (side * 2) * 768;
                uint4 sc = *(const uint4*)(cof + kb);
                uint4 of = *(const uint4*)(cof + 768 + kb);
                h2 u1a = __builtin_elementwise_fma(bch(sc.x), bch(xv.x), bch(of.x));
                h2 u1b = __builtin_elementwise_fma(bch(sc.y), bch(xv.y), bch(of.y));
                h2 u2a = __builtin_elementwise_fma(bch(sc.z), bch(xv.z), bch(of.z));
                h2 u2b = __builtin_elementwise_fma(bch(sc.w), bch(xv.w), bch(of.w));
                uint4 wv;
                wv.x = hcb(__builtin_elementwise_fma(u1a, cA, -(u2a * sA)));
                wv.y = hcb(__builtin_elementwise_fma(u1b, cB, -(u2b * sB)));
                wv.z = hcb(__builtin_elementwise_fma(u1a, sA, u2a * cA));
                wv.w = hcb(__builtin_elementwise_fma(u1b, sB, u2b * cB));
                *(uint4*)&bufb[side * 8192 + sw] = wv;
            }
            {   // t1 build (same x/cs, different coefs)
                const unsigned short* cof = scofh + ((2 + side) * 2) * 768;
                uint4 sc = *(const uint4*)(cof + kb);
                uint4 of = *(const uint4*)(cof + 768 + kb);
                h2 u1a = __builtin_elementwise_fma(bch(sc.x), bch(xv.x), bch(of.x));
                h2 u1b = __builtin_elementwise_fma(bch(sc.y), bch(xv.y), bch(of.y));
                h2 u2a = __builtin_elementwise_fma(bch(sc.z), bch(xv.z), bch(of.z));
                h2 u2b = __builtin_elementwise_fma(bch(sc.w), bch(xv.w), bch(of.w));
                uint4 wv;
                wv.x = hcb(__builtin_elementwise_fma(u1a, cA, -(u2a * sA)));
                wv.y = hcb(__builtin_elementwise_fma(u1b, cB, -(u2b * sB)));
                wv.z = hcb(__builtin_elementwise_fma(u1a, sA, u2a * cA));
                wv.w = hcb(__builtin_elementwise_fma(u1b, sB, u2b * cB));
                *(uint4*)&bufb[16384 + side * 8192 + sw] = wv;
            }
        }
        __syncthreads();

        __builtin_amdgcn_s_setprio(1);
        {   // t0 MFMA
            const unsigned short* tD = bufb;
            const unsigned short* tA = bufb + 8192;
            #pragma unroll
            for (int kk = 0; kk < 64; kk += 32) {
                f16x8 af[2], bf2[2];
                #pragma unroll
                for (int fi = 0; fi < 2; ++fi)
                    af[fi] = *(const f16x8*)&tD[(wrow + fi * 16 + lr) * 64 + (gr0 ^ kk)];
                #pragma unroll
                for (int fj = 0; fj < 2; ++fj)
                    bf2[fj] = *(const f16x8*)&tA[(wcol + fj * 16 + lr) * 64 + (gr0 ^ kk)];
                #pragma unroll
                for (int fi = 0; fi < 2; ++fi)
                    #pragma unroll
                    for (int fj = 0; fj < 2; ++fj)
                        a0[fi][fj] = __builtin_amdgcn_mfma_f32_16x16x32_f16(
                            af[fi], bf2[fj], a0[fi][fj], 0, 0, 0);
            }
        }
        {   // t1 MFMA
            const unsigned short* tD = bufb + 16384;
            const unsigned short* tA = bufb + 24576;
            #pragma unroll
            for (int kk = 0; kk < 64; kk += 32) {
                f16x8 af[2], bf2[2];
                #pragma unroll
                for (int fi = 0; fi < 2; ++fi)
                    af[fi] = *(const f16x8*)&tD[(wrow + fi * 16 + lr) * 64 + (gr0 ^ kk)];
                #pragma unroll
                for (int fj = 0; fj < 2; ++fj)
                    bf2[fj] = *(const f16x8*)&tA[(wcol + fj * 16 + lr) * 64 + (gr0 ^ kk)];
                #pragma unroll
                for (int fi = 0; fi < 2; ++fi)
                    #pragma unroll
                    for (int fj = 0; fj < 2; ++fj)
                        a1[fi][fj] = __builtin_amdgcn_mfma_f32_16x16x32_f16(
                            af[fi], bf2[fj], a1[fi][fj], 0, 0, 0);
            }
        }
        __builtin_amdgcn_s_setprio(0);
    }

    // ---- epilogue ----
    // Every wave here passed bar(ch=11): all builds done; ch=11's mfma reads
    // buf1 [64,128KB) -> buf0 region [0,64KB) is free for staging.
    #pragma unroll
    for (int fi = 0; fi < 2; ++fi) {
        #pragma unroll
        for (int rr = 0; rr < 4; ++rr) {
            int d = wrow + fi * 16 + lq * 4 + rr;
            int vd = vD[d];
            #pragma unroll
            for (int fj = 0; fj < 2; ++fj) {
                int a = wcol + fj * 16 + lr;
                int va = vA[a];
                float x0 = a0[fi][fj][rr];
                float v0 = 0.0f;
                if (vd && va) v0 = (x0 > 15.0f) ? x0 : __logf(1.0f + __expf(x0));
                smem[d * P_ + a] = packbf1(v0);
                float x1 = a1[fi][fj][rr];
                float v1 = 0.0f;
                if (vd && va) v1 = (x1 > 15.0f) ? x1 : __logf(1.0f + __expf(x1));
                smem[16384 + d * P_ + a] = packbf1(v1);
            }
        }
    }
    __syncthreads();
    const uint4* s4 = (const uint4*)smem;
    uint4* d40 = (uint4*)(w1 + (size_t)((b * 2 + sign) * T_ + t0) * (P_ * P_));
    for (int i = tid; i < 2048; i += 1024) d40[i] = s4[i];
    if (t1ok) {
        uint4* d41 = (uint4*)(w1 + (size_t)((b * 2 + sign) * T_ + t1) * (P_ * P_));
        for (int i = tid; i < 2048; i += 1024) d41[i] = s4[2048 + i];
    }
}

// ---------------- C: transpose bf16 [b][sign][t][d][a] -> f32 [b][d][a][sign*T+t] ----------------
__global__ __launch_bounds__(256) void transpose_out(const __hip_bfloat16* __restrict__ w1,
                                                     float* __restrict__ pred) {
    __shared__ float tile[64 * 129];
    int blk = blockIdx.x;            // bs*128*6 + d*6 + tt   (3072 blocks)
    int tt = blk % 6;
    int d = (blk / 6) % P_;
    int bs = blk / (6 * P_);         // b*2+sign
    int b = bs >> 1, sign = bs & 1;
    int t0 = tt * 64;
    int tcnt = min(64, T_ - t0);
    int tid = threadIdx.x;

    const __hip_bfloat16* src = w1 + (size_t)bs * T_ * P_ * P_ + (size_t)d * P_;
    for (int e = tid; e < tcnt * P_; e += 256) {
        int i = e >> 7, a = e & 127;
        tile[i * 129 + a] = __bfloat162float(src[(size_t)(t0 + i) * P_ * P_ + a]);
    }
    __syncthreads();
    float* dst = pred + ((size_t)(b * P_ + d) * P_) * TT_ + sign * T_ + t0;
    for (int e = tid; e < P_ * 64; e += 256) {
        int a = e >> 6, ii = e & 63;
        if (ii < tcnt) dst[(size_t)a * TT_ + ii] = tile[ii * 129 + a];
    }
}

// ---------------- D: mask fill (MUST run after transpose_out: overwrites w1) ----------------
__global__ void mask_fill(const int* __restrict__ sp, float* __restrict__ mask) {
    int blk = blockIdx.x;            // (b*128+d)*128+a   (32768 blocks)
    int a = blk & 127;
    int d = (blk >> 7) & 127;
    int b = blk >> 14;
    bool vp = (sp[(b * 4 + 0) * P_ + d] >= 0) && (sp[(b * 4 + 1) * P_ + a] >= 0);
    bool vn = (sp[(b * 4 + 2) * P_ + d] >= 0) && (sp[(b * 4 + 3) * P_ + a] >= 0);
    float* dst = mask + (size_t)blk * TT_;
    for (int st = threadIdx.x; st < TT_; st += blockDim.x)
        dst[st] = (st < T_ ? vp : vn) ? 1.0f : 0.0f;
}

extern "C" void kernel_launch(void* const* d_in, const int* in_sizes, int n_in,
                              void* d_out, int out_size, void* d_ws, size_t ws_size,
                              hipStream_t stream) {
    const float* emb  = (const float*)d_in[0];
    const float* w    = (const float*)d_in[1];
    const float* bias = (const float*)d_in[2];
    const float* rpd  = (const float*)d_in[3];
    const float* rpa  = (const float*)d_in[4];
    const float* rnd  = (const float*)d_in[5];
    const float* rna  = (const float*)d_in[6];
    const int*   org  = (const int*)d_in[7];
    const int*   sp   = (const int*)d_in[8];

    float* out = (float*)d_out;
    float* ws  = (float*)d_ws;
    unsigned short* xhh = (unsigned short*)(ws + XHH_OFF);
    unsigned short* csh = (unsigned short*)(ws + CSH_OFF);
    double* invf = (double*)(ws + INVF_OFF);
    unsigned short* xcb = (unsigned short*)(ws + XCB_OFF);
    float* pred  = out;
    float* maskp = out + PRED_ELEMS;
    unsigned short* w1 = (unsigned short*)maskp;   // bf16 staging in mask half

    init_invf<<<1, 384, 0, stream>>>(invf);
    gather_cols<<<1024, 256, 0, stream>>>(emb, sp, xcb);
    rope_table<<<1536, 256, 0, stream>>>(sp, invf, csh);
    dim3 gl(16, 12);
    logits_mfma<<<gl, 256, 0, stream>>>(xcb, w, bias, org, xhh);
    junction_mfma<<<2 * 2 * NT2_, 1024, 0, stream>>>(xhh, csh, rpd, rpa, rnd, rna, org, sp, w1);
    transpose_out<<<2 * 2 * P_ * 6, 256, 0, stream>>>((const __hip_bfloat16*)w1, pred);
    mask_fill<<<32768, 256, 0, stream>>>(sp, maskp);
}